// Round 2
// baseline (699.366 us; speedup 1.0000x reference)
//
#include <hip/hip_runtime.h>
#include <hip/hip_bf16.h>

#define N_NODES 50000
#define N_EDGES 1600000
#define BATCH   16384
#define HID     128

using short8  = __attribute__((ext_vector_type(8))) short;
using floatx4 = __attribute__((ext_vector_type(4))) float;
typedef unsigned short ushort_t;

__device__ __forceinline__ float bflo(unsigned u){ return __uint_as_float(u << 16); }
__device__ __forceinline__ float bfhi(unsigned u){ return __uint_as_float(u & 0xffff0000u); }
__device__ __forceinline__ float bf1(ushort_t u){ return __uint_as_float(((unsigned)u) << 16); }
__device__ __forceinline__ ushort_t f2bf(float f){
    unsigned u = __float_as_uint(f);
    return (ushort_t)((u + 0x7fffu + ((u >> 16) & 1u)) >> 16);   // RNE
}
// flag-aware int load: works for int32 and int64 arrays (values < 2^31)
__device__ __forceinline__ int geti(const void* p, long long i, int is64){
    return is64 ? (int)((const long long*)p)[i] : ((const int*)p)[i];
}

// ---------------- dtype detection ----------------
// flags[0]: float tensors are fp32 (else bf16). flags[1]: int tensors are int64.
__global__ void k_detect(const unsigned* __restrict__ xbits,
                         const unsigned* __restrict__ eibits, int* flags){
    if (threadIdx.x == 0 && blockIdx.x == 0){
        int big = 0;
        for (int i = 0; i < 256; ++i){
            unsigned u = xbits[i];
            unsigned e0 = (u >> 7)  & 0xFF;   // exponent of low bf16 half
            unsigned e1 = (u >> 23) & 0xFF;   // exponent of high half / fp32
            if (e0 >= 140) big++;
            if (e1 >= 140) big++;
        }
        flags[0] = (big > 0) ? 1 : 0;
        int oddnz = 0;
        for (int i = 0; i < 256; ++i)
            if (eibits[2*i + 1] != 0) oddnz++;
        flags[1] = (oddnz == 0) ? 1 : 0;
    }
}

// ---------------- canonical bf16 weight arena ----------------
#define NT 19
struct ConvDesc { const void* src[NT]; int cum[NT + 1]; };
__global__ void k_conv(ConvDesc d, ushort_t* __restrict__ dst, const int* __restrict__ flags){
    int i = blockIdx.x*256 + threadIdx.x;
    if (i >= d.cum[NT]) return;
    int seg = 0;
    while (i >= d.cum[seg + 1]) seg++;
    int off = i - d.cum[seg];
    ushort_t v;
    if (flags[0]) v = f2bf(((const float*)d.src[seg])[off]);
    else          v = ((const ushort_t*)d.src[seg])[off];
    dst[i] = v;
}

// ---------------- CSR build ----------------
__global__ void k_zero(int* deg){
    int i = blockIdx.x*256 + threadIdx.x;
    if (i < N_NODES) deg[i] = 0;
}
__global__ void k_count(const void* __restrict__ ei, int* __restrict__ deg,
                        const int* __restrict__ flags){
    int e = blockIdx.x*256 + threadIdx.x;
    if (e < N_EDGES) atomicAdd(&deg[geti(ei, (long long)N_EDGES + e, flags[1])], 1);
}
__global__ void k_scan1(const int* __restrict__ deg, int* __restrict__ off, int* __restrict__ bsum){
    __shared__ int sh[1024];
    int t = threadIdx.x, i = blockIdx.x*1024 + t;
    int v = (i < N_NODES) ? deg[i] : 0;
    sh[t] = v; __syncthreads();
    for (int o = 1; o < 1024; o <<= 1){
        int x = (t >= o) ? sh[t-o] : 0;
        __syncthreads();
        sh[t] += x;
        __syncthreads();
    }
    if (i < N_NODES) off[i] = sh[t] - v;
    if (t == 1023) bsum[blockIdx.x] = sh[1023];
}
__global__ void k_scan2(int* bsum, int* off, int nb){
    if (threadIdx.x == 0 && blockIdx.x == 0){
        int run = 0;
        for (int b = 0; b < nb; ++b){ int t = bsum[b]; bsum[b] = run; run += t; }
        off[N_NODES] = run;
    }
}
__global__ void k_scan3(int* __restrict__ off, int* __restrict__ cur, const int* __restrict__ bsum){
    int i = blockIdx.x*1024 + threadIdx.x;
    if (i < N_NODES){
        int o = off[i] + bsum[blockIdx.x];
        off[i] = o; cur[i] = o;
    }
}
__global__ void k_fill(const void* __restrict__ ei, int* __restrict__ cur,
                       int* __restrict__ csr, const int* __restrict__ flags){
    int e = blockIdx.x*256 + threadIdx.x;
    if (e < N_EDGES){
        int i64 = flags[1];
        int s = geti(ei, e, i64);
        int d = geti(ei, (long long)N_EDGES + e, i64);
        int p = atomicAdd(&cur[d], 1);
        csr[p] = s;
    }
}

// ---------------- GEMM: out[M,256] = in[M,K] @ [W0 | W1] (each [K,128]) ----------------
// mfma_f32_16x16x32_bf16: A[m=lane&15][k=quad*8+j], B[k=quad*8+j][n=lane&15],
// C/D: col=lane&15, row=quad*4+reg.
template<int KSTEPS, bool MF32>
__global__ __launch_bounds__(256)
void k_gemm(const void* __restrict__ in, int S,
            const ushort_t* __restrict__ W0, const ushort_t* __restrict__ W1,
            ushort_t* __restrict__ out, int M, const int* __restrict__ flags)
{
    const int tid  = threadIdx.x;
    const int w    = tid >> 6;
    const int lane = tid & 63;
    const int l16  = lane & 15;
    const int q    = lane >> 4;
    const int n0   = blockIdx.y*64 + w*16;
    const int col  = n0 + l16;
    const ushort_t* Wsel = (col < HID) ? W0 : W1;
    const int wc   = col & (HID-1);
    const int f32  = MF32 ? flags[0] : 0;

    short8 bfrag[KSTEPS];
    #pragma unroll
    for (int kk = 0; kk < KSTEPS; ++kk){
        #pragma unroll
        for (int j = 0; j < 8; ++j)
            bfrag[kk][j] = (short)Wsel[(kk*32 + q*8 + j)*HID + wc];
    }

    const int mt0 = blockIdx.x * 8;
    for (int i = 0; i < 8; ++i){
        int m0 = (mt0 + i) * 16;
        if (m0 >= M) break;
        int m = m0 + l16;
        bool ok = (m < M);
        const ushort_t* arow_h = (const ushort_t*)in + (size_t)m*S + q*8;
        const float*    arow_f = (const float*)in + (size_t)m*S + q*8;
        floatx4 acc = {0.f, 0.f, 0.f, 0.f};
        #pragma unroll
        for (int kk = 0; kk < KSTEPS; ++kk){
            short8 af = {0,0,0,0,0,0,0,0};
            if (ok){
                if (MF32 && f32){
                    #pragma unroll
                    for (int j = 0; j < 8; ++j) af[j] = (short)f2bf(arow_f[kk*32 + j]);
                } else {
                    af = *(const short8*)(arow_h + kk*32);
                }
            }
            acc = __builtin_amdgcn_mfma_f32_16x16x32_bf16(af, bfrag[kk], acc, 0, 0, 0);
        }
        #pragma unroll
        for (int r = 0; r < 4; ++r){
            int row = m0 + q*4 + r;
            if (row < M) out[(size_t)row*256 + col] = f2bf(acc[r]);
        }
    }
}

// ---------------- Aggregation: out[v] = mean(y[csr]) + bias + r[v] (opt relu) ----
__global__ __launch_bounds__(256)
void k_agg(const int* __restrict__ off, const int* __restrict__ csr,
           const ushort_t* __restrict__ yr, const ushort_t* __restrict__ bias,
           ushort_t* __restrict__ out, int do_relu)
{
    int v = blockIdx.x*4 + (threadIdx.x >> 6);
    if (v >= N_NODES) return;
    int l = threadIdx.x & 63;
    int e0 = off[v], e1 = off[v+1];
    const unsigned* base = (const unsigned*)yr;           // row stride 128 uints (256 bf16)
    float a0 = 0.f, a1 = 0.f;
    int p = e0;
    for (; p + 4 <= e1; p += 4){
        int u0 = csr[p], u1 = csr[p+1], u2 = csr[p+2], u3 = csr[p+3];
        unsigned x0 = base[u0*128 + l];
        unsigned x1 = base[u1*128 + l];
        unsigned x2 = base[u2*128 + l];
        unsigned x3 = base[u3*128 + l];
        a0 += bflo(x0); a1 += bfhi(x0);
        a0 += bflo(x1); a1 += bfhi(x1);
        a0 += bflo(x2); a1 += bfhi(x2);
        a0 += bflo(x3); a1 += bfhi(x3);
    }
    for (; p < e1; ++p){
        unsigned x = base[csr[p]*128 + l];
        a0 += bflo(x); a1 += bfhi(x);
    }
    float inv = 1.f / (float)max(e1 - e0, 1);
    unsigned rr = base[v*128 + 64 + l];
    unsigned bb = ((const unsigned*)bias)[l];
    a0 = a0*inv + bflo(rr) + bflo(bb);
    a1 = a1*inv + bfhi(rr) + bfhi(bb);
    if (do_relu){ a0 = fmaxf(a0, 0.f); a1 = fmaxf(a1, 0.f); }
    ((unsigned*)out)[v*64 + l] = (unsigned)f2bf(a0) | ((unsigned)f2bf(a1) << 16);
}

// ---------------- Fused predictor: one wave per batch row ----------------
__global__ __launch_bounds__(256)
void k_pred(const ushort_t* __restrict__ h2,
            const void* __restrict__ srcn, const void* __restrict__ tgtn,
            const ushort_t* __restrict__ ef,
            const ushort_t* __restrict__ ep_w, const ushort_t* __restrict__ ep_b,
            const ushort_t* __restrict__ p1_w, const ushort_t* __restrict__ p1_b,
            const ushort_t* __restrict__ bn_g, const ushort_t* __restrict__ bn_b,
            const ushort_t* __restrict__ bn_m, const ushort_t* __restrict__ bn_v,
            const ushort_t* __restrict__ p2_w, const ushort_t* __restrict__ p2_b,
            const ushort_t* __restrict__ p3_w, const ushort_t* __restrict__ p3_b,
            void* __restrict__ outp, const int* __restrict__ flags)
{
    __shared__ float comb[4][320];
    __shared__ float zb[4][128];
    int wdx = threadIdx.x >> 6, l = threadIdx.x & 63;
    int row = blockIdx.x*4 + wdx;
    int i64 = flags[1];
    int s = geti(srcn, row, i64), t = geti(tgtn, row, i64);
    unsigned us = ((const unsigned*)h2)[s*64 + l];
    unsigned ut = ((const unsigned*)h2)[t*64 + l];
    comb[wdx][2*l]       = bflo(us); comb[wdx][2*l+1]     = bfhi(us);
    comb[wdx][128+2*l]   = bflo(ut); comb[wdx][128+2*l+1] = bfhi(ut);
    float ep = bf1(ep_b[l]);
    #pragma unroll
    for (int k = 0; k < 6; ++k)
        ep += bf1(ef[row*6 + k]) * bf1(ep_w[k*64 + l]);
    comb[wdx][256+l] = fmaxf(ep, 0.f);
    __syncthreads();

    unsigned ub = ((const unsigned*)p1_b)[l];
    float z0 = bflo(ub), z1 = bfhi(ub);
    const unsigned* w1 = (const unsigned*)p1_w + l;
    const float* cb = comb[wdx];
    #pragma unroll 4
    for (int k = 0; k < 320; ++k){
        float ck = cb[k];
        unsigned wv = w1[k*64];
        z0 += ck * bflo(wv);
        z1 += ck * bfhi(wv);
    }
    z0 = fmaxf(z0, 0.f); z1 = fmaxf(z1, 0.f);
    unsigned um = ((const unsigned*)bn_m)[l], uv  = ((const unsigned*)bn_v)[l];
    unsigned ug = ((const unsigned*)bn_g)[l], ubt = ((const unsigned*)bn_b)[l];
    z0 = (z0 - bflo(um)) * __frsqrt_rn(bflo(uv) + 1e-5f) * bflo(ug) + bflo(ubt);
    z1 = (z1 - bfhi(um)) * __frsqrt_rn(bfhi(uv) + 1e-5f) * bfhi(ug) + bfhi(ubt);
    zb[wdx][2*l] = z0; zb[wdx][2*l+1] = z1;
    __syncthreads();

    float a2 = bf1(p2_b[l]);
    const float* zz = zb[wdx];
    #pragma unroll 4
    for (int k = 0; k < 128; ++k)
        a2 += zz[k] * bf1(p2_w[k*64 + l]);
    a2 = fmaxf(a2, 0.f);
    float part = a2 * bf1(p3_w[l]);
    #pragma unroll
    for (int o = 32; o > 0; o >>= 1) part += __shfl_down(part, o, 64);
    if (l == 0){
        float zf = part + bf1(p3_b[0]);
        float sg = 1.f / (1.f + __expf(-zf));
        if (flags[0]) ((float*)outp)[row] = sg;
        else          ((ushort_t*)outp)[row] = f2bf(sg);
    }
}

// canonical arena offsets (ushort units)
#define OFF_WL0 0
#define OFF_WR0 32768
#define OFF_WL1 65536
#define OFF_WR1 81920
#define OFF_B0  98304
#define OFF_B1  98432
#define OFF_EPW 98560
#define OFF_EPB 98944
#define OFF_P1W 99008
#define OFF_P1B 139968
#define OFF_BNG 140096
#define OFF_BNB 140224
#define OFF_BNM 140352
#define OFF_BNV 140480
#define OFF_P2W 140608
#define OFF_P2B 148800
#define OFF_P3W 148864
#define OFF_EF  148928
#define OFF_P3B 247232
#define CW_TOT  247233

extern "C" void kernel_launch(void* const* d_in, const int* in_sizes, int n_in,
                              void* d_out, int out_size, void* d_ws, size_t ws_size,
                              hipStream_t stream)
{
    const void* x    = d_in[0];
    const void* ei   = d_in[1];
    const void* srcn = d_in[2];
    const void* tgtn = d_in[3];

    char* p = (char*)d_ws;
    auto carve = [&](size_t bytes)->char*{ char* r = p; p += (bytes + 511) & ~size_t(511); return r; };
    int* flags = (int*)carve(64);
    int* off   = (int*)carve((N_NODES+1)*4);
    int* cur   = (int*)carve((size_t)N_NODES*4);
    int* deg   = (int*)carve((size_t)N_NODES*4);
    int* bsum  = (int*)carve(64*4);
    int* csr   = (int*)carve((size_t)N_EDGES*4);
    ushort_t* yr = (ushort_t*)carve((size_t)N_NODES*256*2);
    ushort_t* h  = (ushort_t*)carve((size_t)N_NODES*128*2);
    ushort_t* cw = (ushort_t*)carve((size_t)CW_TOT*2);

    k_detect<<<1, 64, 0, stream>>>((const unsigned*)x, (const unsigned*)ei, flags);

    ConvDesc cd;
    const int srcidx[NT] = {5,7,8,10,6,9,11,12,13,14,15,16,17,18,19,20,21,4,22};
    const int lens[NT]   = {32768,32768,16384,16384,128,128,384,64,40960,128,128,128,128,128,8192,64,64,98304,1};
    int run = 0;
    for (int i = 0; i < NT; ++i){ cd.src[i] = d_in[srcidx[i]]; cd.cum[i] = run; run += lens[i]; }
    cd.cum[NT] = run;  // == CW_TOT
    k_conv<<<(CW_TOT+255)/256, 256, 0, stream>>>(cd, cw, flags);

    k_zero <<<(N_NODES+255)/256, 256, 0, stream>>>(deg);
    k_count<<<(N_EDGES+255)/256, 256, 0, stream>>>(ei, deg, flags);
    int nb = (N_NODES + 1023) / 1024;
    k_scan1<<<nb, 1024, 0, stream>>>(deg, off, bsum);
    k_scan2<<<1, 64, 0, stream>>>(bsum, off, nb);
    k_scan3<<<nb, 1024, 0, stream>>>(off, cur, bsum);
    k_fill <<<(N_EDGES+255)/256, 256, 0, stream>>>(ei, cur, csr, flags);

    dim3 g0((3125 + 7) / 8, 4);
    k_gemm<8, true ><<<g0, 256, 0, stream>>>(x, 256, cw+OFF_WL0, cw+OFF_WR0, yr, N_NODES, flags);
    k_agg<<<(N_NODES+3)/4, 256, 0, stream>>>(off, csr, yr, cw+OFF_B0, h, 1);
    k_gemm<4, false><<<g0, 256, 0, stream>>>(h, 128, cw+OFF_WL1, cw+OFF_WR1, yr, N_NODES, flags);
    k_agg<<<(N_NODES+3)/4, 256, 0, stream>>>(off, csr, yr, cw+OFF_B1, h, 0);

    k_pred<<<BATCH/4, 256, 0, stream>>>(h, srcn, tgtn, cw+OFF_EF,
                                        cw+OFF_EPW, cw+OFF_EPB, cw+OFF_P1W, cw+OFF_P1B,
                                        cw+OFF_BNG, cw+OFF_BNB, cw+OFF_BNM, cw+OFF_BNV,
                                        cw+OFF_P2W, cw+OFF_P2B, cw+OFF_P3W, cw+OFF_P3B,
                                        d_out, flags);
}

// Round 3
// 601.639 us; speedup vs baseline: 1.1624x; 1.1624x over previous
//
#include <hip/hip_runtime.h>
#include <hip/hip_bf16.h>

#define N_NODES 50000
#define N_EDGES 1600000
#define BATCH   16384
#define HID     128

using short8  = __attribute__((ext_vector_type(8))) short;
using floatx4 = __attribute__((ext_vector_type(4))) float;
using floatv4 = __attribute__((ext_vector_type(4))) float;
using uint2v  = __attribute__((ext_vector_type(2))) unsigned;
typedef unsigned short ushort_t;

__device__ __forceinline__ float bflo(unsigned u){ return __uint_as_float(u << 16); }
__device__ __forceinline__ float bfhi(unsigned u){ return __uint_as_float(u & 0xffff0000u); }
__device__ __forceinline__ float bf1(ushort_t u){ return __uint_as_float(((unsigned)u) << 16); }
__device__ __forceinline__ ushort_t f2bf(float f){
    unsigned u = __float_as_uint(f);
    return (ushort_t)((u + 0x7fffu + ((u >> 16) & 1u)) >> 16);   // RNE
}
__device__ __forceinline__ int geti(const void* p, long long i, int is64){
    return is64 ? (int)((const long long*)p)[i] : ((const int*)p)[i];
}

// ---------------- dtype detection ----------------
__global__ void k_detect(const unsigned* __restrict__ xbits,
                         const unsigned* __restrict__ eibits, int* flags){
    if (threadIdx.x == 0 && blockIdx.x == 0){
        int big = 0;
        for (int i = 0; i < 256; ++i){
            unsigned u = xbits[i];
            unsigned e0 = (u >> 7)  & 0xFF;
            unsigned e1 = (u >> 23) & 0xFF;
            if (e0 >= 140) big++;
            if (e1 >= 140) big++;
        }
        flags[0] = (big > 0) ? 1 : 0;
        int oddnz = 0;
        for (int i = 0; i < 256; ++i)
            if (eibits[2*i + 1] != 0) oddnz++;
        flags[1] = (oddnz == 0) ? 1 : 0;
    }
}

// ---------------- canonical bf16 weight arena ----------------
#define NT 19
struct ConvDesc { const void* src[NT]; int cum[NT + 1]; };
__global__ void k_conv(ConvDesc d, ushort_t* __restrict__ dst, const int* __restrict__ flags){
    int i = blockIdx.x*256 + threadIdx.x;
    if (i >= d.cum[NT]) return;
    int seg = 0;
    while (i >= d.cum[seg + 1]) seg++;
    int off = i - d.cum[seg];
    ushort_t v;
    if (flags[0]) v = f2bf(((const float*)d.src[seg])[off]);
    else          v = ((const ushort_t*)d.src[seg])[off];
    dst[i] = v;
}

// canonical arena offsets (ushort units)
#define OFF_WL0 0
#define OFF_WR0 32768
#define OFF_WL1 65536
#define OFF_WR1 81920
#define OFF_B0  98304
#define OFF_B1  98432
#define OFF_EPW 98560
#define OFF_EPB 98944
#define OFF_P1W 99008
#define OFF_P1B 139968
#define OFF_BNG 140096
#define OFF_BNB 140224
#define OFF_BNM 140352
#define OFF_BNV 140480
#define OFF_P2W 140608
#define OFF_P2B 148800
#define OFF_P3W 148864
#define OFF_EF  148928
#define OFF_P3B 247232
#define CW_TOT  247233

// ---------------- B pre-pack into MFMA fragment order ----------------
// Bp[kk][c][lane][j] = Wcat[k = kk*32 + (lane>>4)*8 + j][n = c*16 + (lane&15)]
// layer0: kk<8 (65536 shorts), layer1: kk<4 (32768 shorts)
__global__ void k_pack(const ushort_t* __restrict__ cw,
                       ushort_t* __restrict__ bp0, ushort_t* __restrict__ bp1){
    int i = blockIdx.x*256 + threadIdx.x;
    if (i < 65536){
        int j = i & 7, lane = (i >> 3) & 63, c = (i >> 9) & 15, kk = i >> 13;
        int k = kk*32 + (lane >> 4)*8 + j;
        int n = c*16 + (lane & 15);
        bp0[i] = (n < 128) ? cw[OFF_WL0 + k*128 + n] : cw[OFF_WR0 + k*128 + (n-128)];
    } else if (i < 98304){
        int i2 = i - 65536;
        int j = i2 & 7, lane = (i2 >> 3) & 63, c = (i2 >> 9) & 15, kk = i2 >> 13;
        int k = kk*32 + (lane >> 4)*8 + j;
        int n = c*16 + (lane & 15);
        bp1[i2] = (n < 128) ? cw[OFF_WL1 + k*128 + n] : cw[OFF_WR1 + k*128 + (n-128)];
    }
}

// ---------------- x -> bf16 cast (only when fp32 inputs) ----------------
__global__ __launch_bounds__(256)
void k_xcast(const float* __restrict__ x, ushort_t* __restrict__ xbf,
             const int* __restrict__ flags){
    if (!flags[0]) return;
    int i = blockIdx.x*256 + threadIdx.x;          // 3.2M threads, 4 floats each
    floatv4 v = ((const floatv4*)x)[i];
    uint2v o;
    o.x = (unsigned)f2bf(v[0]) | ((unsigned)f2bf(v[1]) << 16);
    o.y = (unsigned)f2bf(v[2]) | ((unsigned)f2bf(v[3]) << 16);
    ((uint2v*)xbf)[i] = o;
}

// ---------------- CSR build ----------------
__global__ void k_zero(int* deg){
    int i = blockIdx.x*256 + threadIdx.x;
    if (i < N_NODES) deg[i] = 0;
}
__global__ void k_count(const void* __restrict__ ei, int* __restrict__ deg,
                        const int* __restrict__ flags){
    int e = blockIdx.x*256 + threadIdx.x;
    if (e < N_EDGES) atomicAdd(&deg[geti(ei, (long long)N_EDGES + e, flags[1])], 1);
}
__global__ void k_scan1(const int* __restrict__ deg, int* __restrict__ off, int* __restrict__ bsum){
    __shared__ int sh[1024];
    int t = threadIdx.x, i = blockIdx.x*1024 + t;
    int v = (i < N_NODES) ? deg[i] : 0;
    sh[t] = v; __syncthreads();
    for (int o = 1; o < 1024; o <<= 1){
        int x = (t >= o) ? sh[t-o] : 0;
        __syncthreads();
        sh[t] += x;
        __syncthreads();
    }
    if (i < N_NODES) off[i] = sh[t] - v;
    if (t == 1023) bsum[blockIdx.x] = sh[1023];
}
__global__ void k_scan2(int* bsum, int* off, int nb){
    if (threadIdx.x == 0 && blockIdx.x == 0){
        int run = 0;
        for (int b = 0; b < nb; ++b){ int t = bsum[b]; bsum[b] = run; run += t; }
        off[N_NODES] = run;
    }
}
__global__ void k_scan3(int* __restrict__ off, int* __restrict__ cur, const int* __restrict__ bsum){
    int i = blockIdx.x*1024 + threadIdx.x;
    if (i < N_NODES){
        int o = off[i] + bsum[blockIdx.x];
        off[i] = o; cur[i] = o;
    }
}
__global__ void k_fill(const void* __restrict__ ei, int* __restrict__ cur,
                       int* __restrict__ csr, const int* __restrict__ flags){
    int e = blockIdx.x*256 + threadIdx.x;
    if (e < N_EDGES){
        int i64 = flags[1];
        int s = geti(ei, e, i64);
        int d = geti(ei, (long long)N_EDGES + e, i64);
        int p = atomicAdd(&cur[d], 1);
        csr[p] = s;
    }
}

// ---------------- GEMM: out[M,256] = A[M,K] @ Wcat[K,256] ----------------
// Block = 64 rows x 256 cols, 4 waves; wave w owns cols [w*64, w*64+64).
// A read exactly once (16B vector frag loads); B from packed frag arena (L2-hot).
// acc[rt][ci]: rt = row-tile (4x16 rows), ci = col-tile within wave (4x16 cols).
template<int KSTEPS, bool MF32>
__global__ __launch_bounds__(256)
void k_gemm2(const void* __restrict__ a_raw, const ushort_t* __restrict__ a_bf,
             const ushort_t* __restrict__ Bp, ushort_t* __restrict__ out,
             int M, const int* __restrict__ flags)
{
    const int lane = threadIdx.x & 63;
    const int w    = threadIdx.x >> 6;
    const int l16  = lane & 15;
    const int q    = lane >> 4;
    const int S    = KSTEPS * 32;
    const int m_base = blockIdx.x * 64;

    const ushort_t* A = (MF32 && flags[0]) ? a_bf : (const ushort_t*)a_raw;

    const ushort_t* arow[4];
    bool ok[4];
    #pragma unroll
    for (int rt = 0; rt < 4; ++rt){
        int m = m_base + rt*16 + l16;
        ok[rt] = (m < M);
        arow[rt] = A + (size_t)(ok[rt] ? m : 0) * S + q*8;
    }
    const short8* bbase = (const short8*)(Bp + (size_t)(w*4)*64*8) + lane;

    floatx4 acc[4][4] = {};
    for (int kk = 0; kk < KSTEPS; ++kk){
        short8 b[4];
        #pragma unroll
        for (int ci = 0; ci < 4; ++ci)
            b[ci] = bbase[(kk*16 + ci)*64];
        short8 a[4];
        #pragma unroll
        for (int rt = 0; rt < 4; ++rt){
            short8 af = {0,0,0,0,0,0,0,0};
            if (ok[rt]) af = *(const short8*)(arow[rt] + kk*32);
            a[rt] = af;
        }
        #pragma unroll
        for (int rt = 0; rt < 4; ++rt)
            #pragma unroll
            for (int ci = 0; ci < 4; ++ci)
                acc[rt][ci] = __builtin_amdgcn_mfma_f32_16x16x32_bf16(a[rt], b[ci], acc[rt][ci], 0, 0, 0);
    }

    #pragma unroll
    for (int rt = 0; rt < 4; ++rt){
        int row_b = m_base + rt*16 + q*4;
        #pragma unroll
        for (int r = 0; r < 4; ++r){
            int row = row_b + r;
            if (row < M){
                #pragma unroll
                for (int ci = 0; ci < 4; ++ci)
                    out[(size_t)row*256 + w*64 + ci*16 + l16] = f2bf(acc[rt][ci][r]);
            }
        }
    }
}

// ---------------- Aggregation: out[v] = mean(y[csr]) + bias + r[v] (opt relu) ----
__global__ __launch_bounds__(256)
void k_agg(const int* __restrict__ off, const int* __restrict__ csr,
           const ushort_t* __restrict__ yr, const ushort_t* __restrict__ bias,
           ushort_t* __restrict__ out, int do_relu)
{
    int v = blockIdx.x*4 + (threadIdx.x >> 6);
    if (v >= N_NODES) return;
    int l = threadIdx.x & 63;
    int e0 = off[v], e1 = off[v+1];
    const unsigned* base = (const unsigned*)yr;
    float a0 = 0.f, a1 = 0.f;
    int p = e0;
    for (; p + 4 <= e1; p += 4){
        int u0 = csr[p], u1 = csr[p+1], u2 = csr[p+2], u3 = csr[p+3];
        unsigned x0 = base[u0*128 + l];
        unsigned x1 = base[u1*128 + l];
        unsigned x2 = base[u2*128 + l];
        unsigned x3 = base[u3*128 + l];
        a0 += bflo(x0); a1 += bfhi(x0);
        a0 += bflo(x1); a1 += bfhi(x1);
        a0 += bflo(x2); a1 += bfhi(x2);
        a0 += bflo(x3); a1 += bfhi(x3);
    }
    for (; p < e1; ++p){
        unsigned x = base[csr[p]*128 + l];
        a0 += bflo(x); a1 += bfhi(x);
    }
    float inv = 1.f / (float)max(e1 - e0, 1);
    unsigned rr = base[v*128 + 64 + l];
    unsigned bb = ((const unsigned*)bias)[l];
    a0 = a0*inv + bflo(rr) + bflo(bb);
    a1 = a1*inv + bfhi(rr) + bfhi(bb);
    if (do_relu){ a0 = fmaxf(a0, 0.f); a1 = fmaxf(a1, 0.f); }
    ((unsigned*)out)[v*64 + l] = (unsigned)f2bf(a0) | ((unsigned)f2bf(a1) << 16);
}

// ---------------- Fused predictor: one wave per batch row ----------------
__global__ __launch_bounds__(256)
void k_pred(const ushort_t* __restrict__ h2,
            const void* __restrict__ srcn, const void* __restrict__ tgtn,
            const ushort_t* __restrict__ ef,
            const ushort_t* __restrict__ ep_w, const ushort_t* __restrict__ ep_b,
            const ushort_t* __restrict__ p1_w, const ushort_t* __restrict__ p1_b,
            const ushort_t* __restrict__ bn_g, const ushort_t* __restrict__ bn_b,
            const ushort_t* __restrict__ bn_m, const ushort_t* __restrict__ bn_v,
            const ushort_t* __restrict__ p2_w, const ushort_t* __restrict__ p2_b,
            const ushort_t* __restrict__ p3_w, const ushort_t* __restrict__ p3_b,
            void* __restrict__ outp, const int* __restrict__ flags)
{
    __shared__ float comb[4][320];
    __shared__ float zb[4][128];
    int wdx = threadIdx.x >> 6, l = threadIdx.x & 63;
    int row = blockIdx.x*4 + wdx;
    int i64 = flags[1];
    int s = geti(srcn, row, i64), t = geti(tgtn, row, i64);
    unsigned us = ((const unsigned*)h2)[s*64 + l];
    unsigned ut = ((const unsigned*)h2)[t*64 + l];
    comb[wdx][2*l]       = bflo(us); comb[wdx][2*l+1]     = bfhi(us);
    comb[wdx][128+2*l]   = bflo(ut); comb[wdx][128+2*l+1] = bfhi(ut);
    float ep = bf1(ep_b[l]);
    #pragma unroll
    for (int k = 0; k < 6; ++k)
        ep += bf1(ef[row*6 + k]) * bf1(ep_w[k*64 + l]);
    comb[wdx][256+l] = fmaxf(ep, 0.f);
    __syncthreads();

    unsigned ub = ((const unsigned*)p1_b)[l];
    float z0 = bflo(ub), z1 = bfhi(ub);
    const unsigned* w1 = (const unsigned*)p1_w + l;
    const float* cb = comb[wdx];
    #pragma unroll 4
    for (int k = 0; k < 320; ++k){
        float ck = cb[k];
        unsigned wv = w1[k*64];
        z0 += ck * bflo(wv);
        z1 += ck * bfhi(wv);
    }
    z0 = fmaxf(z0, 0.f); z1 = fmaxf(z1, 0.f);
    unsigned um = ((const unsigned*)bn_m)[l], uv  = ((const unsigned*)bn_v)[l];
    unsigned ug = ((const unsigned*)bn_g)[l], ubt = ((const unsigned*)bn_b)[l];
    z0 = (z0 - bflo(um)) * __frsqrt_rn(bflo(uv) + 1e-5f) * bflo(ug) + bflo(ubt);
    z1 = (z1 - bfhi(um)) * __frsqrt_rn(bfhi(uv) + 1e-5f) * bfhi(ug) + bfhi(ubt);
    zb[wdx][2*l] = z0; zb[wdx][2*l+1] = z1;
    __syncthreads();

    float a2 = bf1(p2_b[l]);
    const float* zz = zb[wdx];
    #pragma unroll 4
    for (int k = 0; k < 128; ++k)
        a2 += zz[k] * bf1(p2_w[k*64 + l]);
    a2 = fmaxf(a2, 0.f);
    float part = a2 * bf1(p3_w[l]);
    #pragma unroll
    for (int o = 32; o > 0; o >>= 1) part += __shfl_down(part, o, 64);
    if (l == 0){
        float zf = part + bf1(p3_b[0]);
        float sg = 1.f / (1.f + __expf(-zf));
        if (flags[0]) ((float*)outp)[row] = sg;
        else          ((ushort_t*)outp)[row] = f2bf(sg);
    }
}

extern "C" void kernel_launch(void* const* d_in, const int* in_sizes, int n_in,
                              void* d_out, int out_size, void* d_ws, size_t ws_size,
                              hipStream_t stream)
{
    const void* x    = d_in[0];
    const void* ei   = d_in[1];
    const void* srcn = d_in[2];
    const void* tgtn = d_in[3];

    char* p = (char*)d_ws;
    auto carve = [&](size_t bytes)->char*{ char* r = p; p += (bytes + 511) & ~size_t(511); return r; };
    int* flags = (int*)carve(64);
    int* off   = (int*)carve((N_NODES+1)*4);
    int* cur   = (int*)carve((size_t)N_NODES*4);
    int* deg   = (int*)carve((size_t)N_NODES*4);
    int* bsum  = (int*)carve(64*4);
    int* csr   = (int*)carve((size_t)N_EDGES*4);
    ushort_t* yr  = (ushort_t*)carve((size_t)N_NODES*256*2);
    ushort_t* h   = (ushort_t*)carve((size_t)N_NODES*128*2);
    ushort_t* cw  = (ushort_t*)carve((size_t)CW_TOT*2);
    ushort_t* bp0 = (ushort_t*)carve((size_t)65536*2);
    ushort_t* bp1 = (ushort_t*)carve((size_t)32768*2);
    ushort_t* xbf = (ushort_t*)carve((size_t)N_NODES*256*2);

    k_detect<<<1, 64, 0, stream>>>((const unsigned*)x, (const unsigned*)ei, flags);

    ConvDesc cd;
    const int srcidx[NT] = {5,7,8,10,6,9,11,12,13,14,15,16,17,18,19,20,21,4,22};
    const int lens[NT]   = {32768,32768,16384,16384,128,128,384,64,40960,128,128,128,128,128,8192,64,64,98304,1};
    int run = 0;
    for (int i = 0; i < NT; ++i){ cd.src[i] = d_in[srcidx[i]]; cd.cum[i] = run; run += lens[i]; }
    cd.cum[NT] = run;
    k_conv<<<(CW_TOT+255)/256, 256, 0, stream>>>(cd, cw, flags);
    k_pack<<<(98304+255)/256, 256, 0, stream>>>(cw, bp0, bp1);
    k_xcast<<<12500, 256, 0, stream>>>((const float*)x, xbf, flags);

    k_zero <<<(N_NODES+255)/256, 256, 0, stream>>>(deg);
    k_count<<<(N_EDGES+255)/256, 256, 0, stream>>>(ei, deg, flags);
    int nb = (N_NODES + 1023) / 1024;
    k_scan1<<<nb, 1024, 0, stream>>>(deg, off, bsum);
    k_scan2<<<1, 64, 0, stream>>>(bsum, off, nb);
    k_scan3<<<nb, 1024, 0, stream>>>(off, cur, bsum);
    k_fill <<<(N_EDGES+255)/256, 256, 0, stream>>>(ei, cur, csr, flags);

    int gblocks = (N_NODES + 63) / 64;   // 782
    k_gemm2<8, true ><<<gblocks, 256, 0, stream>>>(x, xbf, bp0, yr, N_NODES, flags);
    k_agg<<<(N_NODES+3)/4, 256, 0, stream>>>(off, csr, yr, cw+OFF_B0, h, 1);
    k_gemm2<4, false><<<gblocks, 256, 0, stream>>>(h, nullptr, bp1, yr, N_NODES, flags);
    k_agg<<<(N_NODES+3)/4, 256, 0, stream>>>(off, csr, yr, cw+OFF_B1, h, 0);

    k_pred<<<BATCH/4, 256, 0, stream>>>(h, srcn, tgtn, cw+OFF_EF,
                                        cw+OFF_EPW, cw+OFF_EPB, cw+OFF_P1W, cw+OFF_P1B,
                                        cw+OFF_BNG, cw+OFF_BNB, cw+OFF_BNM, cw+OFF_BNV,
                                        cw+OFF_P2W, cw+OFF_P2B, cw+OFF_P3W, cw+OFF_P3B,
                                        d_out, flags);
}

// Round 4
// 458.758 us; speedup vs baseline: 1.5245x; 1.3115x over previous
//
#include <hip/hip_runtime.h>
#include <hip/hip_bf16.h>

#define N_NODES 50000
#define N_EDGES 1600000
#define BATCH   16384
#define HID     128
#define NBUCK   782          // (N_NODES+63)/64
#define NBLK    1000
#define EPB     1600         // NBLK*EPB == N_EDGES

using short8  = __attribute__((ext_vector_type(8))) short;
using floatx4 = __attribute__((ext_vector_type(4))) float;
using floatv4 = __attribute__((ext_vector_type(4))) float;
using uint2v  = __attribute__((ext_vector_type(2))) unsigned;
typedef unsigned short ushort_t;

__device__ __forceinline__ float bflo(unsigned u){ return __uint_as_float(u << 16); }
__device__ __forceinline__ float bfhi(unsigned u){ return __uint_as_float(u & 0xffff0000u); }
__device__ __forceinline__ float bf1(ushort_t u){ return __uint_as_float(((unsigned)u) << 16); }
__device__ __forceinline__ ushort_t f2bf(float f){
    unsigned u = __float_as_uint(f);
    return (ushort_t)((u + 0x7fffu + ((u >> 16) & 1u)) >> 16);   // RNE
}
__device__ __forceinline__ int geti(const void* p, long long i, int is64){
    return is64 ? (int)((const long long*)p)[i] : ((const int*)p)[i];
}

// ---------------- dtype detection ----------------
__global__ void k_detect(const unsigned* __restrict__ xbits,
                         const unsigned* __restrict__ eibits, int* flags){
    if (threadIdx.x == 0 && blockIdx.x == 0){
        int big = 0;
        for (int i = 0; i < 256; ++i){
            unsigned u = xbits[i];
            unsigned e0 = (u >> 7)  & 0xFF;
            unsigned e1 = (u >> 23) & 0xFF;
            if (e0 >= 140) big++;
            if (e1 >= 140) big++;
        }
        flags[0] = (big > 0) ? 1 : 0;
        int oddnz = 0;
        for (int i = 0; i < 256; ++i)
            if (eibits[2*i + 1] != 0) oddnz++;
        flags[1] = (oddnz == 0) ? 1 : 0;
    }
}

// ---------------- canonical bf16 weight arena ----------------
#define NT 19
struct ConvDesc { const void* src[NT]; int cum[NT + 1]; };
__global__ void k_conv(ConvDesc d, ushort_t* __restrict__ dst, const int* __restrict__ flags){
    int i = blockIdx.x*256 + threadIdx.x;
    if (i >= d.cum[NT]) return;
    int seg = 0;
    while (i >= d.cum[seg + 1]) seg++;
    int off = i - d.cum[seg];
    ushort_t v;
    if (flags[0]) v = f2bf(((const float*)d.src[seg])[off]);
    else          v = ((const ushort_t*)d.src[seg])[off];
    dst[i] = v;
}

// canonical arena offsets (ushort units)
#define OFF_WL0 0
#define OFF_WR0 32768
#define OFF_WL1 65536
#define OFF_WR1 81920
#define OFF_B0  98304
#define OFF_B1  98432
#define OFF_EPW 98560
#define OFF_EPB 98944
#define OFF_P1W 99008
#define OFF_P1B 139968
#define OFF_BNG 140096
#define OFF_BNB 140224
#define OFF_BNM 140352
#define OFF_BNV 140480
#define OFF_P2W 140608
#define OFF_P2B 148800
#define OFF_P3W 148864
#define OFF_EF  148928
#define OFF_P3B 247232
#define CW_TOT  247233

// ---------------- B pre-pack into MFMA fragment order ----------------
__global__ void k_pack(const ushort_t* __restrict__ cw,
                       ushort_t* __restrict__ bp0, ushort_t* __restrict__ bp1){
    int i = blockIdx.x*256 + threadIdx.x;
    if (i < 65536){
        int j = i & 7, lane = (i >> 3) & 63, c = (i >> 9) & 15, kk = i >> 13;
        int k = kk*32 + (lane >> 4)*8 + j;
        int n = c*16 + (lane & 15);
        bp0[i] = (n < 128) ? cw[OFF_WL0 + k*128 + n] : cw[OFF_WR0 + k*128 + (n-128)];
    } else if (i < 98304){
        int i2 = i - 65536;
        int j = i2 & 7, lane = (i2 >> 3) & 63, c = (i2 >> 9) & 15, kk = i2 >> 13;
        int k = kk*32 + (lane >> 4)*8 + j;
        int n = c*16 + (lane & 15);
        bp1[i2] = (n < 128) ? cw[OFF_WL1 + k*128 + n] : cw[OFF_WR1 + k*128 + (n-128)];
    }
}

// ---------------- x -> bf16 cast (only when fp32 inputs) ----------------
__global__ __launch_bounds__(256)
void k_xcast(const float* __restrict__ x, ushort_t* __restrict__ xbf,
             const int* __restrict__ flags){
    if (!flags[0]) return;
    int i = blockIdx.x*256 + threadIdx.x;
    floatv4 v = ((const floatv4*)x)[i];
    uint2v o;
    o.x = (unsigned)f2bf(v[0]) | ((unsigned)f2bf(v[1]) << 16);
    o.y = (unsigned)f2bf(v[2]) | ((unsigned)f2bf(v[3]) << 16);
    ((uint2v*)xbf)[i] = o;
}

// ---------------- bucketed CSR build (atomic-free in global) ----------------
// Pass 1: per-block LDS bucket histogram -> hist[bucket*NBLK + block]
__global__ __launch_bounds__(256)
void kb_hist(const void* __restrict__ ei, int* __restrict__ hist,
             const int* __restrict__ flags){
    __shared__ int lh[NBUCK];
    for (int i = threadIdx.x; i < NBUCK; i += 256) lh[i] = 0;
    __syncthreads();
    int i64 = flags[1];
    int e0 = blockIdx.x * EPB;
    for (int e = e0 + threadIdx.x; e < e0 + EPB; e += 256){
        int d = geti(ei, (long long)N_EDGES + e, i64);
        atomicAdd(&lh[d >> 6], 1);
    }
    __syncthreads();
    for (int i = threadIdx.x; i < NBUCK; i += 256)
        hist[i * NBLK + blockIdx.x] = lh[i];
}

// Pass 1b: exclusive scan each bucket's column (over blocks); total -> btot
__global__ __launch_bounds__(1024)
void kb_scancol(int* __restrict__ hist, int* __restrict__ btot){
    __shared__ int sh[1024];
    int b = blockIdx.x, t = threadIdx.x;
    int v = (t < NBLK) ? hist[b*NBLK + t] : 0;
    sh[t] = v; __syncthreads();
    for (int o = 1; o < 1024; o <<= 1){
        int x = (t >= o) ? sh[t-o] : 0;
        __syncthreads();
        sh[t] += x;
        __syncthreads();
    }
    if (t < NBLK) hist[b*NBLK + t] = sh[t] - v;
    if (t == 1023) btot[b] = sh[1023];
}

// Pass 1c: exclusive scan bucket totals -> bbase; also off[N_NODES]
__global__ __launch_bounds__(1024)
void kb_scanbase(const int* __restrict__ btot, int* __restrict__ bbase,
                 int* __restrict__ off){
    __shared__ int sh[1024];
    int t = threadIdx.x;
    int v = (t < NBUCK) ? btot[t] : 0;
    sh[t] = v; __syncthreads();
    for (int o = 1; o < 1024; o <<= 1){
        int x = (t >= o) ? sh[t-o] : 0;
        __syncthreads();
        sh[t] += x;
        __syncthreads();
    }
    if (t < NBUCK) bbase[t] = sh[t] - v;
    if (t == 0){ bbase[NBUCK] = N_EDGES; off[N_NODES] = N_EDGES; }
}

// Pass 2: scatter packed (src | (d&63)<<16) into per-bucket streams, LDS cursors
__global__ __launch_bounds__(256)
void kb_scatter(const void* __restrict__ ei, const int* __restrict__ hist,
                const int* __restrict__ bbase, unsigned* __restrict__ ebuf,
                const int* __restrict__ flags){
    __shared__ int lcur[NBUCK];
    for (int i = threadIdx.x; i < NBUCK; i += 256)
        lcur[i] = bbase[i] + hist[i*NBLK + blockIdx.x];
    __syncthreads();
    int i64 = flags[1];
    int e0 = blockIdx.x * EPB;
    for (int e = e0 + threadIdx.x; e < e0 + EPB; e += 256){
        int s = geti(ei, e, i64);
        int d = geti(ei, (long long)N_EDGES + e, i64);
        int p = atomicAdd(&lcur[d >> 6], 1);
        ebuf[p] = (unsigned)s | ((unsigned)(d & 63) << 16);
    }
}

// Pass 3: one block per bucket: local deg/scan/cursor in LDS, write off + u16 csr
__global__ __launch_bounds__(256)
void kb_csr(const unsigned* __restrict__ ebuf, const int* __restrict__ bbase,
            ushort_t* __restrict__ csr, int* __restrict__ off){
    __shared__ int ldeg[64];
    int b = blockIdx.x, t = threadIdx.x;
    int ebase = bbase[b], eend = bbase[b+1];
    if (t < 64) ldeg[t] = 0;
    __syncthreads();
    for (int i = ebase + t; i < eend; i += 256)
        atomicAdd(&ldeg[(ebuf[i] >> 16) & 63], 1);
    __syncthreads();
    if (t < 64){
        int v = ldeg[t];
        int sum = v;
        #pragma unroll
        for (int o = 1; o < 64; o <<= 1){
            int x = __shfl_up(sum, o, 64);
            if (t >= o) sum += x;
        }
        int excl = sum - v;
        int node = b*64 + t;
        if (node < N_NODES) off[node] = ebase + excl;
        ldeg[t] = excl;                 // becomes cursor
    }
    __syncthreads();
    for (int i = ebase + t; i < eend; i += 256){
        unsigned u = ebuf[i];
        int p = atomicAdd(&ldeg[(u >> 16) & 63], 1);
        csr[ebase + p] = (ushort_t)(u & 0xffffu);
    }
}

// ---------------- GEMM: out[M,256] = A[M,K] @ Wcat[K,256] ----------------
template<int KSTEPS, bool MF32>
__global__ __launch_bounds__(256)
void k_gemm2(const void* __restrict__ a_raw, const ushort_t* __restrict__ a_bf,
             const ushort_t* __restrict__ Bp, ushort_t* __restrict__ out,
             int M, const int* __restrict__ flags)
{
    const int lane = threadIdx.x & 63;
    const int w    = threadIdx.x >> 6;
    const int l16  = lane & 15;
    const int q    = lane >> 4;
    const int S    = KSTEPS * 32;
    const int m_base = blockIdx.x * 64;

    const ushort_t* A = (MF32 && flags[0]) ? a_bf : (const ushort_t*)a_raw;

    const ushort_t* arow[4];
    bool ok[4];
    #pragma unroll
    for (int rt = 0; rt < 4; ++rt){
        int m = m_base + rt*16 + l16;
        ok[rt] = (m < M);
        arow[rt] = A + (size_t)(ok[rt] ? m : 0) * S + q*8;
    }
    const short8* bbase = (const short8*)(Bp + (size_t)(w*4)*64*8) + lane;

    floatx4 acc[4][4] = {};
    for (int kk = 0; kk < KSTEPS; ++kk){
        short8 b[4];
        #pragma unroll
        for (int ci = 0; ci < 4; ++ci)
            b[ci] = bbase[(kk*16 + ci)*64];
        short8 a[4];
        #pragma unroll
        for (int rt = 0; rt < 4; ++rt){
            short8 af = {0,0,0,0,0,0,0,0};
            if (ok[rt]) af = *(const short8*)(arow[rt] + kk*32);
            a[rt] = af;
        }
        #pragma unroll
        for (int rt = 0; rt < 4; ++rt)
            #pragma unroll
            for (int ci = 0; ci < 4; ++ci)
                acc[rt][ci] = __builtin_amdgcn_mfma_f32_16x16x32_bf16(a[rt], b[ci], acc[rt][ci], 0, 0, 0);
    }

    #pragma unroll
    for (int rt = 0; rt < 4; ++rt){
        int row_b = m_base + rt*16 + q*4;
        #pragma unroll
        for (int r = 0; r < 4; ++r){
            int row = row_b + r;
            if (row < M){
                #pragma unroll
                for (int ci = 0; ci < 4; ++ci)
                    out[(size_t)row*256 + w*64 + ci*16 + l16] = f2bf(acc[rt][ci][r]);
            }
        }
    }
}

// ---------------- Aggregation: out[v] = mean(y[csr]) + bias + r[v] (opt relu) ----
__global__ __launch_bounds__(256)
void k_agg(const int* __restrict__ off, const ushort_t* __restrict__ csr,
           const ushort_t* __restrict__ yr, const ushort_t* __restrict__ bias,
           ushort_t* __restrict__ out, int do_relu)
{
    int v = blockIdx.x*4 + (threadIdx.x >> 6);
    if (v >= N_NODES) return;
    int l = threadIdx.x & 63;
    int e0 = off[v], e1 = off[v+1];
    const unsigned* base = (const unsigned*)yr;
    float a0 = 0.f, a1 = 0.f;
    int p = e0;
    for (; p + 4 <= e1; p += 4){
        int u0 = csr[p], u1 = csr[p+1], u2 = csr[p+2], u3 = csr[p+3];
        unsigned x0 = base[u0*128 + l];
        unsigned x1 = base[u1*128 + l];
        unsigned x2 = base[u2*128 + l];
        unsigned x3 = base[u3*128 + l];
        a0 += bflo(x0); a1 += bfhi(x0);
        a0 += bflo(x1); a1 += bfhi(x1);
        a0 += bflo(x2); a1 += bfhi(x2);
        a0 += bflo(x3); a1 += bfhi(x3);
    }
    for (; p < e1; ++p){
        unsigned x = base[csr[p]*128 + l];
        a0 += bflo(x); a1 += bfhi(x);
    }
    float inv = 1.f / (float)max(e1 - e0, 1);
    unsigned rr = base[v*128 + 64 + l];
    unsigned bb = ((const unsigned*)bias)[l];
    a0 = a0*inv + bflo(rr) + bflo(bb);
    a1 = a1*inv + bfhi(rr) + bfhi(bb);
    if (do_relu){ a0 = fmaxf(a0, 0.f); a1 = fmaxf(a1, 0.f); }
    ((unsigned*)out)[v*64 + l] = (unsigned)f2bf(a0) | ((unsigned)f2bf(a1) << 16);
}

// ---------------- Fused predictor: one wave per batch row ----------------
__global__ __launch_bounds__(256)
void k_pred(const ushort_t* __restrict__ h2,
            const void* __restrict__ srcn, const void* __restrict__ tgtn,
            const ushort_t* __restrict__ ef,
            const ushort_t* __restrict__ ep_w, const ushort_t* __restrict__ ep_b,
            const ushort_t* __restrict__ p1_w, const ushort_t* __restrict__ p1_b,
            const ushort_t* __restrict__ bn_g, const ushort_t* __restrict__ bn_b,
            const ushort_t* __restrict__ bn_m, const ushort_t* __restrict__ bn_v,
            const ushort_t* __restrict__ p2_w, const ushort_t* __restrict__ p2_b,
            const ushort_t* __restrict__ p3_w, const ushort_t* __restrict__ p3_b,
            void* __restrict__ outp, const int* __restrict__ flags)
{
    __shared__ float comb[4][320];
    __shared__ float zb[4][128];
    int wdx = threadIdx.x >> 6, l = threadIdx.x & 63;
    int row = blockIdx.x*4 + wdx;
    int i64 = flags[1];
    int s = geti(srcn, row, i64), t = geti(tgtn, row, i64);
    unsigned us = ((const unsigned*)h2)[s*64 + l];
    unsigned ut = ((const unsigned*)h2)[t*64 + l];
    comb[wdx][2*l]       = bflo(us); comb[wdx][2*l+1]     = bfhi(us);
    comb[wdx][128+2*l]   = bflo(ut); comb[wdx][128+2*l+1] = bfhi(ut);
    float ep = bf1(ep_b[l]);
    #pragma unroll
    for (int k = 0; k < 6; ++k)
        ep += bf1(ef[row*6 + k]) * bf1(ep_w[k*64 + l]);
    comb[wdx][256+l] = fmaxf(ep, 0.f);
    __syncthreads();

    unsigned ub = ((const unsigned*)p1_b)[l];
    float z0 = bflo(ub), z1 = bfhi(ub);
    const unsigned* w1 = (const unsigned*)p1_w + l;
    const float* cb = comb[wdx];
    #pragma unroll 4
    for (int k = 0; k < 320; ++k){
        float ck = cb[k];
        unsigned wv = w1[k*64];
        z0 += ck * bflo(wv);
        z1 += ck * bfhi(wv);
    }
    z0 = fmaxf(z0, 0.f); z1 = fmaxf(z1, 0.f);
    unsigned um = ((const unsigned*)bn_m)[l], uv  = ((const unsigned*)bn_v)[l];
    unsigned ug = ((const unsigned*)bn_g)[l], ubt = ((const unsigned*)bn_b)[l];
    z0 = (z0 - bflo(um)) * __frsqrt_rn(bflo(uv) + 1e-5f) * bflo(ug) + bflo(ubt);
    z1 = (z1 - bfhi(um)) * __frsqrt_rn(bfhi(uv) + 1e-5f) * bfhi(ug) + bfhi(ubt);
    zb[wdx][2*l] = z0; zb[wdx][2*l+1] = z1;
    __syncthreads();

    float a2 = bf1(p2_b[l]);
    const float* zz = zb[wdx];
    #pragma unroll 4
    for (int k = 0; k < 128; ++k)
        a2 += zz[k] * bf1(p2_w[k*64 + l]);
    a2 = fmaxf(a2, 0.f);
    float part = a2 * bf1(p3_w[l]);
    #pragma unroll
    for (int o = 32; o > 0; o >>= 1) part += __shfl_down(part, o, 64);
    if (l == 0){
        float zf = part + bf1(p3_b[0]);
        float sg = 1.f / (1.f + __expf(-zf));
        if (flags[0]) ((float*)outp)[row] = sg;
        else          ((ushort_t*)outp)[row] = f2bf(sg);
    }
}

extern "C" void kernel_launch(void* const* d_in, const int* in_sizes, int n_in,
                              void* d_out, int out_size, void* d_ws, size_t ws_size,
                              hipStream_t stream)
{
    const void* x    = d_in[0];
    const void* ei   = d_in[1];
    const void* srcn = d_in[2];
    const void* tgtn = d_in[3];

    char* p = (char*)d_ws;
    auto carve = [&](size_t bytes)->char*{ char* r = p; p += (bytes + 511) & ~size_t(511); return r; };
    int* flags = (int*)carve(64);
    int* off   = (int*)carve((N_NODES+1)*4);
    int* btot  = (int*)carve(NBUCK*4);
    int* bbase = (int*)carve((NBUCK+1)*4);
    ushort_t* csr = (ushort_t*)carve((size_t)N_EDGES*2);
    ushort_t* yr  = (ushort_t*)carve((size_t)N_NODES*256*2);
    ushort_t* h   = (ushort_t*)carve((size_t)N_NODES*128*2);
    ushort_t* cw  = (ushort_t*)carve((size_t)CW_TOT*2);
    ushort_t* bp0 = (ushort_t*)carve((size_t)65536*2);
    ushort_t* bp1 = (ushort_t*)carve((size_t)32768*2);
    ushort_t* xbf = (ushort_t*)carve((size_t)N_NODES*256*2);

    // alias scratch that dies before k_gemm2 writes yr:
    int*      hist = (int*)yr;                         // 3.128 MB
    unsigned* ebuf = (unsigned*)((char*)yr + 8u*1024*1024);  // 6.4 MB

    k_detect<<<1, 64, 0, stream>>>((const unsigned*)x, (const unsigned*)ei, flags);

    ConvDesc cd;
    const int srcidx[NT] = {5,7,8,10,6,9,11,12,13,14,15,16,17,18,19,20,21,4,22};
    const int lens[NT]   = {32768,32768,16384,16384,128,128,384,64,40960,128,128,128,128,128,8192,64,64,98304,1};
    int run = 0;
    for (int i = 0; i < NT; ++i){ cd.src[i] = d_in[srcidx[i]]; cd.cum[i] = run; run += lens[i]; }
    cd.cum[NT] = run;
    k_conv<<<(CW_TOT+255)/256, 256, 0, stream>>>(cd, cw, flags);
    k_pack<<<(98304+255)/256, 256, 0, stream>>>(cw, bp0, bp1);
    k_xcast<<<12500, 256, 0, stream>>>((const float*)x, xbf, flags);

    kb_hist    <<<NBLK, 256, 0, stream>>>(ei, hist, flags);
    kb_scancol <<<NBUCK, 1024, 0, stream>>>(hist, btot);
    kb_scanbase<<<1, 1024, 0, stream>>>(btot, bbase, off);
    kb_scatter <<<NBLK, 256, 0, stream>>>(ei, hist, bbase, ebuf, flags);
    kb_csr     <<<NBUCK, 256, 0, stream>>>(ebuf, bbase, csr, off);

    int gblocks = (N_NODES + 63) / 64;   // 782
    k_gemm2<8, true ><<<gblocks, 256, 0, stream>>>(x, xbf, bp0, yr, N_NODES, flags);
    k_agg<<<(N_NODES+3)/4, 256, 0, stream>>>(off, csr, yr, cw+OFF_B0, h, 1);
    k_gemm2<4, false><<<gblocks, 256, 0, stream>>>(h, nullptr, bp1, yr, N_NODES, flags);
    k_agg<<<(N_NODES+3)/4, 256, 0, stream>>>(off, csr, yr, cw+OFF_B1, h, 0);

    k_pred<<<BATCH/4, 256, 0, stream>>>(h, srcn, tgtn, cw+OFF_EF,
                                        cw+OFF_EPW, cw+OFF_EPB, cw+OFF_P1W, cw+OFF_P1B,
                                        cw+OFF_BNG, cw+OFF_BNB, cw+OFF_BNM, cw+OFF_BNV,
                                        cw+OFF_P2W, cw+OFF_P2B, cw+OFF_P3W, cw+OFF_P3B,
                                        d_out, flags);
}

// Round 5
// 394.276 us; speedup vs baseline: 1.7738x; 1.1635x over previous
//
#include <hip/hip_runtime.h>
#include <hip/hip_bf16.h>

#define N_NODES 50000
#define N_EDGES 1600000
#define BATCH   16384
#define HID     128
#define NBUCK   782          // (N_NODES+63)/64
#define NBLK    1000
#define EPB     1600         // NBLK*EPB == N_EDGES

using short8  = __attribute__((ext_vector_type(8))) short;
using floatx4 = __attribute__((ext_vector_type(4))) float;
using floatv4 = __attribute__((ext_vector_type(4))) float;
using uint2v  = __attribute__((ext_vector_type(2))) unsigned;
typedef unsigned short ushort_t;

__device__ __forceinline__ float bflo(unsigned u){ return __uint_as_float(u << 16); }
__device__ __forceinline__ float bfhi(unsigned u){ return __uint_as_float(u & 0xffff0000u); }
__device__ __forceinline__ float bf1(ushort_t u){ return __uint_as_float(((unsigned)u) << 16); }
__device__ __forceinline__ ushort_t f2bf(float f){
    unsigned u = __float_as_uint(f);
    return (ushort_t)((u + 0x7fffu + ((u >> 16) & 1u)) >> 16);   // RNE
}
__device__ __forceinline__ int geti(const void* p, long long i, int is64){
    return is64 ? (int)((const long long*)p)[i] : ((const int*)p)[i];
}

// ---------------- dtype detection ----------------
__global__ void k_detect(const unsigned* __restrict__ xbits,
                         const unsigned* __restrict__ eibits, int* flags){
    if (threadIdx.x == 0 && blockIdx.x == 0){
        int big = 0;
        for (int i = 0; i < 256; ++i){
            unsigned u = xbits[i];
            unsigned e0 = (u >> 7)  & 0xFF;
            unsigned e1 = (u >> 23) & 0xFF;
            if (e0 >= 140) big++;
            if (e1 >= 140) big++;
        }
        flags[0] = (big > 0) ? 1 : 0;
        int oddnz = 0;
        for (int i = 0; i < 256; ++i)
            if (eibits[2*i + 1] != 0) oddnz++;
        flags[1] = (oddnz == 0) ? 1 : 0;
    }
}

// ---------------- canonical bf16 weight arena ----------------
#define NT 19
struct ConvDesc { const void* src[NT]; int cum[NT + 1]; };
__global__ void k_conv(ConvDesc d, ushort_t* __restrict__ dst, const int* __restrict__ flags){
    int i = blockIdx.x*256 + threadIdx.x;
    if (i >= d.cum[NT]) return;
    int seg = 0;
    while (i >= d.cum[seg + 1]) seg++;
    int off = i - d.cum[seg];
    ushort_t v;
    if (flags[0]) v = f2bf(((const float*)d.src[seg])[off]);
    else          v = ((const ushort_t*)d.src[seg])[off];
    dst[i] = v;
}

// canonical arena offsets (ushort units)
#define OFF_WL0 0
#define OFF_WR0 32768
#define OFF_WL1 65536
#define OFF_WR1 81920
#define OFF_B0  98304
#define OFF_B1  98432
#define OFF_EPW 98560
#define OFF_EPB 98944
#define OFF_P1W 99008
#define OFF_P1B 139968
#define OFF_BNG 140096
#define OFF_BNB 140224
#define OFF_BNM 140352
#define OFF_BNV 140480
#define OFF_P2W 140608
#define OFF_P2B 148800
#define OFF_P3W 148864
#define OFF_EF  148928
#define OFF_P3B 247232
#define CW_TOT  247233

// ---------------- weight pre-pack into MFMA fragment order + BN fold ----------------
#define PACK_TOT 147584
__global__ void k_pack(const ushort_t* __restrict__ cw,
                       ushort_t* __restrict__ bp0, ushort_t* __restrict__ bp1,
                       ushort_t* __restrict__ bpp1, ushort_t* __restrict__ bpp2,
                       float* __restrict__ bnf){
    int i = blockIdx.x*256 + threadIdx.x;
    if (i < 65536){
        int j = i & 7, lane = (i >> 3) & 63, c = (i >> 9) & 15, kk = i >> 13;
        int k = kk*32 + (lane >> 4)*8 + j;
        int n = c*16 + (lane & 15);
        bp0[i] = (n < 128) ? cw[OFF_WL0 + k*128 + n] : cw[OFF_WR0 + k*128 + (n-128)];
    } else if (i < 98304){
        int i2 = i - 65536;
        int j = i2 & 7, lane = (i2 >> 3) & 63, c = (i2 >> 9) & 15, kk = i2 >> 13;
        int k = kk*32 + (lane >> 4)*8 + j;
        int n = c*16 + (lane & 15);
        bp1[i2] = (n < 128) ? cw[OFF_WL1 + k*128 + n] : cw[OFF_WR1 + k*128 + (n-128)];
    } else if (i < 139264){
        int i2 = i - 98304;                     // p1_w [320][128] -> frag order
        int j = i2 & 7, lane = (i2 >> 3) & 63, ct = (i2 >> 9) & 7, kk = i2 >> 12;
        int k = kk*32 + (lane >> 4)*8 + j;
        int n = ct*16 + (lane & 15);
        bpp1[i2] = cw[OFF_P1W + k*128 + n];
    } else if (i < 147456){
        int i2 = i - 139264;                    // p2_w [128][64] -> frag order
        int j = i2 & 7, lane = (i2 >> 3) & 63, ct = (i2 >> 9) & 3, kk = i2 >> 11;
        int k = kk*32 + (lane >> 4)*8 + j;
        int n = ct*16 + (lane & 15);
        bpp2[i2] = cw[OFF_P2W + k*64 + n];
    } else if (i < PACK_TOT){
        int n = i - 147456;                     // BN fold: scale/shift fp32
        float g = bf1(cw[OFF_BNG + n]), b = bf1(cw[OFF_BNB + n]);
        float m = bf1(cw[OFF_BNM + n]), v = bf1(cw[OFF_BNV + n]);
        float sc = g / sqrtf(v + 1e-5f);
        bnf[n] = sc; bnf[128 + n] = b - m*sc;
    }
}

// ---------------- x -> bf16 cast (only when fp32 inputs) ----------------
__global__ __launch_bounds__(256)
void k_xcast(const float* __restrict__ x, ushort_t* __restrict__ xbf,
             const int* __restrict__ flags){
    if (!flags[0]) return;
    int i = blockIdx.x*256 + threadIdx.x;
    floatv4 v = ((const floatv4*)x)[i];
    uint2v o;
    o.x = (unsigned)f2bf(v[0]) | ((unsigned)f2bf(v[1]) << 16);
    o.y = (unsigned)f2bf(v[2]) | ((unsigned)f2bf(v[3]) << 16);
    ((uint2v*)xbf)[i] = o;
}

// ---------------- bucketed CSR build (atomic-free in global) ----------------
__global__ __launch_bounds__(256)
void kb_hist(const void* __restrict__ ei, int* __restrict__ hist,
             const int* __restrict__ flags){
    __shared__ int lh[NBUCK];
    for (int i = threadIdx.x; i < NBUCK; i += 256) lh[i] = 0;
    __syncthreads();
    int i64 = flags[1];
    int e0 = blockIdx.x * EPB;
    for (int e = e0 + threadIdx.x; e < e0 + EPB; e += 256){
        int d = geti(ei, (long long)N_EDGES + e, i64);
        atomicAdd(&lh[d >> 6], 1);
    }
    __syncthreads();
    for (int i = threadIdx.x; i < NBUCK; i += 256)
        hist[i * NBLK + blockIdx.x] = lh[i];
}

__global__ __launch_bounds__(1024)
void kb_scancol(int* __restrict__ hist, int* __restrict__ btot){
    __shared__ int sh[1024];
    int b = blockIdx.x, t = threadIdx.x;
    int v = (t < NBLK) ? hist[b*NBLK + t] : 0;
    sh[t] = v; __syncthreads();
    for (int o = 1; o < 1024; o <<= 1){
        int x = (t >= o) ? sh[t-o] : 0;
        __syncthreads();
        sh[t] += x;
        __syncthreads();
    }
    if (t < NBLK) hist[b*NBLK + t] = sh[t] - v;
    if (t == 1023) btot[b] = sh[1023];
}

__global__ __launch_bounds__(1024)
void kb_scanbase(const int* __restrict__ btot, int* __restrict__ bbase,
                 int* __restrict__ off){
    __shared__ int sh[1024];
    int t = threadIdx.x;
    int v = (t < NBUCK) ? btot[t] : 0;
    sh[t] = v; __syncthreads();
    for (int o = 1; o < 1024; o <<= 1){
        int x = (t >= o) ? sh[t-o] : 0;
        __syncthreads();
        sh[t] += x;
        __syncthreads();
    }
    if (t < NBUCK) bbase[t] = sh[t] - v;
    if (t == 0){ bbase[NBUCK] = N_EDGES; off[N_NODES] = N_EDGES; }
}

__global__ __launch_bounds__(256)
void kb_scatter(const void* __restrict__ ei, const int* __restrict__ hist,
                const int* __restrict__ bbase, unsigned* __restrict__ ebuf,
                const int* __restrict__ flags){
    __shared__ int lcur[NBUCK];
    for (int i = threadIdx.x; i < NBUCK; i += 256)
        lcur[i] = bbase[i] + hist[i*NBLK + blockIdx.x];
    __syncthreads();
    int i64 = flags[1];
    int e0 = blockIdx.x * EPB;
    for (int e = e0 + threadIdx.x; e < e0 + EPB; e += 256){
        int s = geti(ei, e, i64);
        int d = geti(ei, (long long)N_EDGES + e, i64);
        int p = atomicAdd(&lcur[d >> 6], 1);
        ebuf[p] = (unsigned)s | ((unsigned)(d & 63) << 16);
    }
}

__global__ __launch_bounds__(256)
void kb_csr(const unsigned* __restrict__ ebuf, const int* __restrict__ bbase,
            ushort_t* __restrict__ csr, int* __restrict__ off){
    __shared__ int ldeg[64];
    int b = blockIdx.x, t = threadIdx.x;
    int ebase = bbase[b], eend = bbase[b+1];
    if (t < 64) ldeg[t] = 0;
    __syncthreads();
    for (int i = ebase + t; i < eend; i += 256)
        atomicAdd(&ldeg[(ebuf[i] >> 16) & 63], 1);
    __syncthreads();
    if (t < 64){
        int v = ldeg[t];
        int sum = v;
        #pragma unroll
        for (int o = 1; o < 64; o <<= 1){
            int x = __shfl_up(sum, o, 64);
            if (t >= o) sum += x;
        }
        int excl = sum - v;
        int node = b*64 + t;
        if (node < N_NODES) off[node] = ebase + excl;
        ldeg[t] = excl;
    }
    __syncthreads();
    for (int i = ebase + t; i < eend; i += 256){
        unsigned u = ebuf[i];
        int p = atomicAdd(&ldeg[(u >> 16) & 63], 1);
        csr[ebase + p] = (ushort_t)(u & 0xffffu);
    }
}

// ---------------- GEMM: out[M,256] = A[M,K] @ Wcat[K,256] ----------------
template<int KSTEPS, bool MF32>
__global__ __launch_bounds__(256)
void k_gemm2(const void* __restrict__ a_raw, const ushort_t* __restrict__ a_bf,
             const ushort_t* __restrict__ Bp, ushort_t* __restrict__ out,
             int M, const int* __restrict__ flags)
{
    const int lane = threadIdx.x & 63;
    const int w    = threadIdx.x >> 6;
    const int l16  = lane & 15;
    const int q    = lane >> 4;
    const int S    = KSTEPS * 32;
    const int m_base = blockIdx.x * 64;

    const ushort_t* A = (MF32 && flags[0]) ? a_bf : (const ushort_t*)a_raw;

    const ushort_t* arow[4];
    bool ok[4];
    #pragma unroll
    for (int rt = 0; rt < 4; ++rt){
        int m = m_base + rt*16 + l16;
        ok[rt] = (m < M);
        arow[rt] = A + (size_t)(ok[rt] ? m : 0) * S + q*8;
    }
    const short8* bbase = (const short8*)(Bp + (size_t)(w*4)*64*8) + lane;

    floatx4 acc[4][4] = {};
    for (int kk = 0; kk < KSTEPS; ++kk){
        short8 b[4];
        #pragma unroll
        for (int ci = 0; ci < 4; ++ci)
            b[ci] = bbase[(kk*16 + ci)*64];
        short8 a[4];
        #pragma unroll
        for (int rt = 0; rt < 4; ++rt){
            short8 af = {0,0,0,0,0,0,0,0};
            if (ok[rt]) af = *(const short8*)(arow[rt] + kk*32);
            a[rt] = af;
        }
        #pragma unroll
        for (int rt = 0; rt < 4; ++rt)
            #pragma unroll
            for (int ci = 0; ci < 4; ++ci)
                acc[rt][ci] = __builtin_amdgcn_mfma_f32_16x16x32_bf16(a[rt], b[ci], acc[rt][ci], 0, 0, 0);
    }

    #pragma unroll
    for (int rt = 0; rt < 4; ++rt){
        int row_b = m_base + rt*16 + q*4;
        #pragma unroll
        for (int r = 0; r < 4; ++r){
            int row = row_b + r;
            if (row < M){
                #pragma unroll
                for (int ci = 0; ci < 4; ++ci)
                    out[(size_t)row*256 + w*64 + ci*16 + l16] = f2bf(acc[rt][ci][r]);
            }
        }
    }
}

// ---------------- Aggregation: out[v] = mean(y[csr]) + bias + r[v] (opt relu) ----
__global__ __launch_bounds__(256)
void k_agg(const int* __restrict__ off, const ushort_t* __restrict__ csr,
           const ushort_t* __restrict__ yr, const ushort_t* __restrict__ bias,
           ushort_t* __restrict__ out, int do_relu)
{
    int v = blockIdx.x*4 + (threadIdx.x >> 6);
    if (v >= N_NODES) return;
    int l = threadIdx.x & 63;
    int e0 = off[v], e1 = off[v+1];
    const unsigned* base = (const unsigned*)yr;
    float a0 = 0.f, a1 = 0.f;
    int p = e0;
    for (; p + 4 <= e1; p += 4){
        int u0 = csr[p], u1 = csr[p+1], u2 = csr[p+2], u3 = csr[p+3];
        unsigned x0 = base[u0*128 + l];
        unsigned x1 = base[u1*128 + l];
        unsigned x2 = base[u2*128 + l];
        unsigned x3 = base[u3*128 + l];
        a0 += bflo(x0); a1 += bfhi(x0);
        a0 += bflo(x1); a1 += bfhi(x1);
        a0 += bflo(x2); a1 += bfhi(x2);
        a0 += bflo(x3); a1 += bfhi(x3);
    }
    for (; p < e1; ++p){
        unsigned x = base[csr[p]*128 + l];
        a0 += bflo(x); a1 += bfhi(x);
    }
    float inv = 1.f / (float)max(e1 - e0, 1);
    unsigned rr = base[v*128 + 64 + l];
    unsigned bb = ((const unsigned*)bias)[l];
    a0 = a0*inv + bflo(rr) + bflo(bb);
    a1 = a1*inv + bfhi(rr) + bfhi(bb);
    if (do_relu){ a0 = fmaxf(a0, 0.f); a1 = fmaxf(a1, 0.f); }
    ((unsigned*)out)[v*64 + l] = (unsigned)f2bf(a0) | ((unsigned)f2bf(a1) << 16);
}

// ---------------- MFMA predictor: one block = 64 batch rows ----------------
__global__ __launch_bounds__(256)
void k_pred2(const ushort_t* __restrict__ h2,
             const void* __restrict__ srcn, const void* __restrict__ tgtn,
             const ushort_t* __restrict__ cw, const ushort_t* __restrict__ bpp1,
             const ushort_t* __restrict__ bpp2, const float* __restrict__ bnf,
             void* __restrict__ outp, const int* __restrict__ flags)
{
    __shared__ ushort_t comb[64][328];    // 320 cols + 8 pad (2-way LDS = free)
    __shared__ ushort_t zbuf[64][136];
    __shared__ ushort_t z2buf[64][68];
    __shared__ float    partial[4][64];
    __shared__ int      sid[64], tid_[64];

    const int t    = threadIdx.x;
    const int lane = t & 63;
    const int w    = t >> 6;
    const int l16  = lane & 15;
    const int q    = lane >> 4;
    const int row0 = blockIdx.x * 64;
    const int i64  = flags[1];

    if (t < 64){ sid[t] = geti(srcn, row0 + t, i64); tid_[t] = geti(tgtn, row0 + t, i64); }
    __syncthreads();

    const unsigned* h2u = (const unsigned*)h2;
    // gather src/tgt embeddings (coalesced 256B per row)
    #pragma unroll 4
    for (int r = w*16; r < w*16 + 16; ++r){
        unsigned us = h2u[(size_t)sid[r]*64 + lane];
        unsigned ut = h2u[(size_t)tid_[r]*64 + lane];
        *(unsigned*)&comb[r][2*lane]       = us;
        *(unsigned*)&comb[r][128 + 2*lane] = ut;
    }
    // edge processor: thread t -> row t>>2, cols (t&3)*16..+16
    {
        int r = t >> 2, c0 = (t & 3) * 16;
        float efv[6];
        #pragma unroll
        for (int k = 0; k < 6; ++k) efv[k] = bf1(cw[OFF_EF + (row0 + r)*6 + k]);
        #pragma unroll
        for (int c = 0; c < 16; ++c){
            int n = c0 + c;
            float a = bf1(cw[OFF_EPB + n]);
            #pragma unroll
            for (int k = 0; k < 6; ++k) a += efv[k] * bf1(cw[OFF_EPW + k*64 + n]);
            comb[r][256 + n] = f2bf(fmaxf(a, 0.f));
        }
    }
    __syncthreads();

    // z1 = relu(comb @ p1_w + p1_b); BN folded (scale/shift)
    floatx4 acc[4][2] = {};
    for (int kk = 0; kk < 10; ++kk){
        short8 a[4];
        #pragma unroll
        for (int rt = 0; rt < 4; ++rt)
            a[rt] = *(const short8*)&comb[rt*16 + l16][kk*32 + q*8];
        #pragma unroll
        for (int ci = 0; ci < 2; ++ci){
            short8 b = *(const short8*)&bpp1[(((kk*8) + (w*2 + ci))*64 + lane)*8];
            #pragma unroll
            for (int rt = 0; rt < 4; ++rt)
                acc[rt][ci] = __builtin_amdgcn_mfma_f32_16x16x32_bf16(a[rt], b, acc[rt][ci], 0, 0, 0);
        }
    }
    #pragma unroll
    for (int ci = 0; ci < 2; ++ci){
        int n = w*32 + ci*16 + l16;
        float b1v = bf1(cw[OFF_P1B + n]);
        float sc = bnf[n], sh = bnf[128 + n];
        #pragma unroll
        for (int rt = 0; rt < 4; ++rt)
            #pragma unroll
            for (int r = 0; r < 4; ++r){
                float v = fmaxf(acc[rt][ci][r] + b1v, 0.f) * sc + sh;
                zbuf[rt*16 + q*4 + r][n] = f2bf(v);
            }
    }
    __syncthreads();

    // z2 = relu(z1 @ p2_w + p2_b)
    floatx4 acc2[4] = {};
    for (int kk = 0; kk < 4; ++kk){
        short8 b = *(const short8*)&bpp2[(((kk*4) + w)*64 + lane)*8];
        #pragma unroll
        for (int rt = 0; rt < 4; ++rt){
            short8 a = *(const short8*)&zbuf[rt*16 + l16][kk*32 + q*8];
            acc2[rt] = __builtin_amdgcn_mfma_f32_16x16x32_bf16(a, b, acc2[rt], 0, 0, 0);
        }
    }
    {
        int n = w*16 + l16;
        float b2v = bf1(cw[OFF_P2B + n]);
        #pragma unroll
        for (int rt = 0; rt < 4; ++rt)
            #pragma unroll
            for (int r = 0; r < 4; ++r)
                z2buf[rt*16 + q*4 + r][n] = f2bf(fmaxf(acc2[rt][r] + b2v, 0.f));
    }
    __syncthreads();

    // out = sigmoid(z2 @ p3_w + p3_b)
    {
        int r = t & 63, seg = t >> 6;
        float s = 0.f;
        #pragma unroll
        for (int c = 0; c < 16; ++c){
            int n = seg*16 + c;
            s += bf1(z2buf[r][n]) * bf1(cw[OFF_P3W + n]);
        }
        partial[seg][r] = s;
    }
    __syncthreads();
    if (t < 64){
        float zf = partial[0][t] + partial[1][t] + partial[2][t] + partial[3][t] + bf1(cw[OFF_P3B]);
        float sg = 1.f / (1.f + __expf(-zf));
        if (flags[0]) ((float*)outp)[row0 + t] = sg;
        else          ((ushort_t*)outp)[row0 + t] = f2bf(sg);
    }
}

extern "C" void kernel_launch(void* const* d_in, const int* in_sizes, int n_in,
                              void* d_out, int out_size, void* d_ws, size_t ws_size,
                              hipStream_t stream)
{
    const void* x    = d_in[0];
    const void* ei   = d_in[1];
    const void* srcn = d_in[2];
    const void* tgtn = d_in[3];

    char* p = (char*)d_ws;
    auto carve = [&](size_t bytes)->char*{ char* r = p; p += (bytes + 511) & ~size_t(511); return r; };
    int* flags = (int*)carve(64);
    int* off   = (int*)carve((N_NODES+1)*4);
    int* btot  = (int*)carve(NBUCK*4);
    int* bbase = (int*)carve((NBUCK+1)*4);
    ushort_t* csr = (ushort_t*)carve((size_t)N_EDGES*2);
    ushort_t* yr  = (ushort_t*)carve((size_t)N_NODES*256*2);
    ushort_t* h   = (ushort_t*)carve((size_t)N_NODES*128*2);
    ushort_t* cw  = (ushort_t*)carve((size_t)CW_TOT*2);
    ushort_t* bp0 = (ushort_t*)carve((size_t)65536*2);
    ushort_t* bp1 = (ushort_t*)carve((size_t)32768*2);
    ushort_t* bpp1= (ushort_t*)carve((size_t)40960*2);
    ushort_t* bpp2= (ushort_t*)carve((size_t)8192*2);
    float*    bnf = (float*)carve(256*4);
    ushort_t* xbf = (ushort_t*)carve((size_t)N_NODES*256*2);

    // alias scratch that dies before k_gemm2 writes yr:
    int*      hist = (int*)yr;                               // 3.128 MB
    unsigned* ebuf = (unsigned*)((char*)yr + 8u*1024*1024);  // 6.4 MB

    k_detect<<<1, 64, 0, stream>>>((const unsigned*)x, (const unsigned*)ei, flags);

    ConvDesc cd;
    const int srcidx[NT] = {5,7,8,10,6,9,11,12,13,14,15,16,17,18,19,20,21,4,22};
    const int lens[NT]   = {32768,32768,16384,16384,128,128,384,64,40960,128,128,128,128,128,8192,64,64,98304,1};
    int run = 0;
    for (int i = 0; i < NT; ++i){ cd.src[i] = d_in[srcidx[i]]; cd.cum[i] = run; run += lens[i]; }
    cd.cum[NT] = run;
    k_conv<<<(CW_TOT+255)/256, 256, 0, stream>>>(cd, cw, flags);
    k_pack<<<(PACK_TOT+255)/256, 256, 0, stream>>>(cw, bp0, bp1, bpp1, bpp2, bnf);
    k_xcast<<<12500, 256, 0, stream>>>((const float*)x, xbf, flags);

    kb_hist    <<<NBLK, 256, 0, stream>>>(ei, hist, flags);
    kb_scancol <<<NBUCK, 1024, 0, stream>>>(hist, btot);
    kb_scanbase<<<1, 1024, 0, stream>>>(btot, bbase, off);
    kb_scatter <<<NBLK, 256, 0, stream>>>(ei, hist, bbase, ebuf, flags);
    kb_csr     <<<NBUCK, 256, 0, stream>>>(ebuf, bbase, csr, off);

    int gblocks = (N_NODES + 63) / 64;   // 782
    k_gemm2<8, true ><<<gblocks, 256, 0, stream>>>(x, xbf, bp0, yr, N_NODES, flags);
    k_agg<<<(N_NODES+3)/4, 256, 0, stream>>>(off, csr, yr, cw+OFF_B0, h, 1);
    k_gemm2<4, false><<<gblocks, 256, 0, stream>>>(h, nullptr, bp1, yr, N_NODES, flags);
    k_agg<<<(N_NODES+3)/4, 256, 0, stream>>>(off, csr, yr, cw+OFF_B1, h, 0);

    k_pred2<<<BATCH/64, 256, 0, stream>>>(h, srcn, tgtn, cw, bpp1, bpp2, bnf, d_out, flags);
}

// Round 6
// 388.189 us; speedup vs baseline: 1.8016x; 1.0157x over previous
//
#include <hip/hip_runtime.h>
#include <hip/hip_bf16.h>

#define N_NODES 50000
#define N_EDGES 1600000
#define BATCH   16384
#define HID     128
#define NBUCK   782          // (N_NODES+63)/64
#define NBLK    1000
#define EPB     1600         // NBLK*EPB == N_EDGES

using short8  = __attribute__((ext_vector_type(8))) short;
using floatx4 = __attribute__((ext_vector_type(4))) float;
using floatv4 = __attribute__((ext_vector_type(4))) float;
using uint2v  = __attribute__((ext_vector_type(2))) unsigned;
using uintx4  = __attribute__((ext_vector_type(4))) unsigned;
typedef unsigned short ushort_t;

__device__ __forceinline__ float bflo(unsigned u){ return __uint_as_float(u << 16); }
__device__ __forceinline__ float bfhi(unsigned u){ return __uint_as_float(u & 0xffff0000u); }
__device__ __forceinline__ float bf1(ushort_t u){ return __uint_as_float(((unsigned)u) << 16); }
__device__ __forceinline__ ushort_t f2bf(float f){
    unsigned u = __float_as_uint(f);
    return (ushort_t)((u + 0x7fffu + ((u >> 16) & 1u)) >> 16);   // RNE
}
__device__ __forceinline__ int geti(const void* p, long long i, int is64){
    return is64 ? (int)((const long long*)p)[i] : ((const int*)p)[i];
}

// ---------------- dtype detection ----------------
__global__ void k_detect(const unsigned* __restrict__ xbits,
                         const unsigned* __restrict__ eibits, int* flags){
    if (threadIdx.x == 0 && blockIdx.x == 0){
        int big = 0;
        for (int i = 0; i < 256; ++i){
            unsigned u = xbits[i];
            unsigned e0 = (u >> 7)  & 0xFF;
            unsigned e1 = (u >> 23) & 0xFF;
            if (e0 >= 140) big++;
            if (e1 >= 140) big++;
        }
        flags[0] = (big > 0) ? 1 : 0;
        int oddnz = 0;
        for (int i = 0; i < 256; ++i)
            if (eibits[2*i + 1] != 0) oddnz++;
        flags[1] = (oddnz == 0) ? 1 : 0;
    }
}

// ---------------- canonical bf16 weight arena ----------------
#define NT 19
struct ConvDesc { const void* src[NT]; int cum[NT + 1]; };
__global__ void k_conv(ConvDesc d, ushort_t* __restrict__ dst, const int* __restrict__ flags){
    int i = blockIdx.x*256 + threadIdx.x;
    if (i >= d.cum[NT]) return;
    int seg = 0;
    while (i >= d.cum[seg + 1]) seg++;
    int off = i - d.cum[seg];
    ushort_t v;
    if (flags[0]) v = f2bf(((const float*)d.src[seg])[off]);
    else          v = ((const ushort_t*)d.src[seg])[off];
    dst[i] = v;
}

// canonical arena offsets (ushort units)
#define OFF_WL0 0
#define OFF_WR0 32768
#define OFF_WL1 65536
#define OFF_WR1 81920
#define OFF_B0  98304
#define OFF_B1  98432
#define OFF_EPW 98560
#define OFF_EPB 98944
#define OFF_P1W 99008
#define OFF_P1B 139968
#define OFF_BNG 140096
#define OFF_BNB 140224
#define OFF_BNM 140352
#define OFF_BNV 140480
#define OFF_P2W 140608
#define OFF_P2B 148800
#define OFF_P3W 148864
#define OFF_EF  148928
#define OFF_P3B 247232
#define CW_TOT  247233

// ---------------- weight pre-pack into MFMA fragment order + BN fold ----------------
#define PACK_TOT 147584
__global__ void k_pack(const ushort_t* __restrict__ cw,
                       ushort_t* __restrict__ bp0, ushort_t* __restrict__ bp1,
                       ushort_t* __restrict__ bpp1, ushort_t* __restrict__ bpp2,
                       float* __restrict__ bnf){
    int i = blockIdx.x*256 + threadIdx.x;
    if (i < 65536){
        int j = i & 7, lane = (i >> 3) & 63, c = (i >> 9) & 15, kk = i >> 13;
        int k = kk*32 + (lane >> 4)*8 + j;
        int n = c*16 + (lane & 15);
        bp0[i] = (n < 128) ? cw[OFF_WL0 + k*128 + n] : cw[OFF_WR0 + k*128 + (n-128)];
    } else if (i < 98304){
        int i2 = i - 65536;
        int j = i2 & 7, lane = (i2 >> 3) & 63, c = (i2 >> 9) & 15, kk = i2 >> 13;
        int k = kk*32 + (lane >> 4)*8 + j;
        int n = c*16 + (lane & 15);
        bp1[i2] = (n < 128) ? cw[OFF_WL1 + k*128 + n] : cw[OFF_WR1 + k*128 + (n-128)];
    } else if (i < 139264){
        int i2 = i - 98304;                     // p1_w [320][128] -> frag order
        int j = i2 & 7, lane = (i2 >> 3) & 63, ct = (i2 >> 9) & 7, kk = i2 >> 12;
        int k = kk*32 + (lane >> 4)*8 + j;
        int n = ct*16 + (lane & 15);
        bpp1[i2] = cw[OFF_P1W + k*128 + n];
    } else if (i < 147456){
        int i2 = i - 139264;                    // p2_w [128][64] -> frag order
        int j = i2 & 7, lane = (i2 >> 3) & 63, ct = (i2 >> 9) & 3, kk = i2 >> 11;
        int k = kk*32 + (lane >> 4)*8 + j;
        int n = ct*16 + (lane & 15);
        bpp2[i2] = cw[OFF_P2W + k*64 + n];
    } else if (i < PACK_TOT){
        int n = i - 147456;                     // BN fold: scale/shift fp32
        float g = bf1(cw[OFF_BNG + n]), b = bf1(cw[OFF_BNB + n]);
        float m = bf1(cw[OFF_BNM + n]), v = bf1(cw[OFF_BNV + n]);
        float sc = g / sqrtf(v + 1e-5f);
        bnf[n] = sc; bnf[128 + n] = b - m*sc;
    }
}

// ---------------- x -> bf16 cast (only when fp32 inputs) ----------------
__global__ __launch_bounds__(256)
void k_xcast(const float* __restrict__ x, ushort_t* __restrict__ xbf,
             const int* __restrict__ flags){
    if (!flags[0]) return;
    int i = blockIdx.x*256 + threadIdx.x;
    floatv4 v = ((const floatv4*)x)[i];
    uint2v o;
    o.x = (unsigned)f2bf(v[0]) | ((unsigned)f2bf(v[1]) << 16);
    o.y = (unsigned)f2bf(v[2]) | ((unsigned)f2bf(v[3]) << 16);
    ((uint2v*)xbf)[i] = o;
}

// ---------------- bucketed CSR build (atomic-free in global) ----------------
__global__ __launch_bounds__(256)
void kb_hist(const void* __restrict__ ei, int* __restrict__ hist,
             const int* __restrict__ flags){
    __shared__ int lh[NBUCK];
    for (int i = threadIdx.x; i < NBUCK; i += 256) lh[i] = 0;
    __syncthreads();
    int i64 = flags[1];
    int e0 = blockIdx.x * EPB;
    for (int e = e0 + threadIdx.x; e < e0 + EPB; e += 256){
        int d = geti(ei, (long long)N_EDGES + e, i64);
        atomicAdd(&lh[d >> 6], 1);
    }
    __syncthreads();
    for (int i = threadIdx.x; i < NBUCK; i += 256)
        hist[i * NBLK + blockIdx.x] = lh[i];
}

__global__ __launch_bounds__(1024)
void kb_scancol(int* __restrict__ hist, int* __restrict__ btot){
    __shared__ int sh[1024];
    int b = blockIdx.x, t = threadIdx.x;
    int v = (t < NBLK) ? hist[b*NBLK + t] : 0;
    sh[t] = v; __syncthreads();
    for (int o = 1; o < 1024; o <<= 1){
        int x = (t >= o) ? sh[t-o] : 0;
        __syncthreads();
        sh[t] += x;
        __syncthreads();
    }
    if (t < NBLK) hist[b*NBLK + t] = sh[t] - v;
    if (t == 1023) btot[b] = sh[1023];
}

__global__ __launch_bounds__(1024)
void kb_scanbase(const int* __restrict__ btot, int* __restrict__ bbase,
                 int* __restrict__ off){
    __shared__ int sh[1024];
    int t = threadIdx.x;
    int v = (t < NBUCK) ? btot[t] : 0;
    sh[t] = v; __syncthreads();
    for (int o = 1; o < 1024; o <<= 1){
        int x = (t >= o) ? sh[t-o] : 0;
        __syncthreads();
        sh[t] += x;
        __syncthreads();
    }
    if (t < NBUCK) bbase[t] = sh[t] - v;
    if (t == 0){ bbase[NBUCK] = N_EDGES; off[N_NODES] = N_EDGES; }
}

__global__ __launch_bounds__(256)
void kb_scatter(const void* __restrict__ ei, const int* __restrict__ hist,
                const int* __restrict__ bbase, unsigned* __restrict__ ebuf,
                const int* __restrict__ flags){
    __shared__ int lcur[NBUCK];
    for (int i = threadIdx.x; i < NBUCK; i += 256)
        lcur[i] = bbase[i] + hist[i*NBLK + blockIdx.x];
    __syncthreads();
    int i64 = flags[1];
    int e0 = blockIdx.x * EPB;
    for (int e = e0 + threadIdx.x; e < e0 + EPB; e += 256){
        int s = geti(ei, e, i64);
        int d = geti(ei, (long long)N_EDGES + e, i64);
        int p = atomicAdd(&lcur[d >> 6], 1);
        ebuf[p] = (unsigned)s | ((unsigned)(d & 63) << 16);
    }
}

__global__ __launch_bounds__(256)
void kb_csr(const unsigned* __restrict__ ebuf, const int* __restrict__ bbase,
            ushort_t* __restrict__ csr, int* __restrict__ off){
    __shared__ int ldeg[64];
    int b = blockIdx.x, t = threadIdx.x;
    int ebase = bbase[b], eend = bbase[b+1];
    if (t < 64) ldeg[t] = 0;
    __syncthreads();
    for (int i = ebase + t; i < eend; i += 256)
        atomicAdd(&ldeg[(ebuf[i] >> 16) & 63], 1);
    __syncthreads();
    if (t < 64){
        int v = ldeg[t];
        int sum = v;
        #pragma unroll
        for (int o = 1; o < 64; o <<= 1){
            int x = __shfl_up(sum, o, 64);
            if (t >= o) sum += x;
        }
        int excl = sum - v;
        int node = b*64 + t;
        if (node < N_NODES) off[node] = ebase + excl;
        ldeg[t] = excl;
    }
    __syncthreads();
    for (int i = ebase + t; i < eend; i += 256){
        unsigned u = ebuf[i];
        int p = atomicAdd(&ldeg[(u >> 16) & 63], 1);
        csr[ebase + p] = (ushort_t)(u & 0xffffu);
    }
}

// ---------------- GEMM: out[M,256] = A[M,K] @ Wcat[K,256] ----------------
template<int KSTEPS, bool MF32>
__global__ __launch_bounds__(256)
void k_gemm2(const void* __restrict__ a_raw, const ushort_t* __restrict__ a_bf,
             const ushort_t* __restrict__ Bp, ushort_t* __restrict__ out,
             int M, const int* __restrict__ flags)
{
    const int lane = threadIdx.x & 63;
    const int w    = threadIdx.x >> 6;
    const int l16  = lane & 15;
    const int q    = lane >> 4;
    const int S    = KSTEPS * 32;
    const int m_base = blockIdx.x * 64;

    const ushort_t* A = (MF32 && flags[0]) ? a_bf : (const ushort_t*)a_raw;

    const ushort_t* arow[4];
    bool ok[4];
    #pragma unroll
    for (int rt = 0; rt < 4; ++rt){
        int m = m_base + rt*16 + l16;
        ok[rt] = (m < M);
        arow[rt] = A + (size_t)(ok[rt] ? m : 0) * S + q*8;
    }
    const short8* bbase = (const short8*)(Bp + (size_t)(w*4)*64*8) + lane;

    floatx4 acc[4][4] = {};
    for (int kk = 0; kk < KSTEPS; ++kk){
        short8 b[4];
        #pragma unroll
        for (int ci = 0; ci < 4; ++ci)
            b[ci] = bbase[(kk*16 + ci)*64];
        short8 a[4];
        #pragma unroll
        for (int rt = 0; rt < 4; ++rt){
            short8 af = {0,0,0,0,0,0,0,0};
            if (ok[rt]) af = *(const short8*)(arow[rt] + kk*32);
            a[rt] = af;
        }
        #pragma unroll
        for (int rt = 0; rt < 4; ++rt)
            #pragma unroll
            for (int ci = 0; ci < 4; ++ci)
                acc[rt][ci] = __builtin_amdgcn_mfma_f32_16x16x32_bf16(a[rt], b[ci], acc[rt][ci], 0, 0, 0);
    }

    #pragma unroll
    for (int rt = 0; rt < 4; ++rt){
        int row_b = m_base + rt*16 + q*4;
        #pragma unroll
        for (int r = 0; r < 4; ++r){
            int row = row_b + r;
            if (row < M){
                #pragma unroll
                for (int ci = 0; ci < 4; ++ci)
                    out[(size_t)row*256 + w*64 + ci*16 + l16] = f2bf(acc[rt][ci][r]);
            }
        }
    }
}

// ---------------- Aggregation: out[v] = mean(y[csr]) + bias + r[v] (opt relu) ----
// Wave per node. Lane groups g=l>>4 handle edge p+g; lane covers 16B of the
// 256B y-row (dwordx4 gather). 4 edges (1KB) in flight per iteration.
__global__ __launch_bounds__(256)
void k_agg(const int* __restrict__ off, const ushort_t* __restrict__ csr,
           const ushort_t* __restrict__ yr, const ushort_t* __restrict__ bias,
           ushort_t* __restrict__ out, int do_relu)
{
    int v = blockIdx.x*4 + (threadIdx.x >> 6);
    if (v >= N_NODES) return;
    const int l = threadIdx.x & 63;
    const int g = l >> 4;          // edge subgroup
    const int c = l & 15;          // 16B chunk of row: bf16 cols c*8..c*8+8
    int e0 = off[v], e1 = off[v+1];

    float a0=0,a1=0,a2=0,a3=0,a4=0,a5=0,a6=0,a7=0;
    int p = e0;
    for (; p + 4 <= e1; p += 4){
        int u = csr[p + g];
        uintx4 d = *(const uintx4*)(yr + (size_t)u*256 + c*8);
        a0 += bflo(d.x); a1 += bfhi(d.x);
        a2 += bflo(d.y); a3 += bfhi(d.y);
        a4 += bflo(d.z); a5 += bfhi(d.z);
        a6 += bflo(d.w); a7 += bfhi(d.w);
    }
    if (p + g < e1){               // tail (0-3 edges)
        int u = csr[p + g];
        uintx4 d = *(const uintx4*)(yr + (size_t)u*256 + c*8);
        a0 += bflo(d.x); a1 += bfhi(d.x);
        a2 += bflo(d.y); a3 += bfhi(d.y);
        a4 += bflo(d.z); a5 += bfhi(d.z);
        a6 += bflo(d.w); a7 += bfhi(d.w);
    }
    // reduce across the 4 groups (xor 16, xor 32)
    #pragma unroll
    for (int m = 16; m <= 32; m <<= 1){
        a0 += __shfl_xor(a0, m, 64); a1 += __shfl_xor(a1, m, 64);
        a2 += __shfl_xor(a2, m, 64); a3 += __shfl_xor(a3, m, 64);
        a4 += __shfl_xor(a4, m, 64); a5 += __shfl_xor(a5, m, 64);
        a6 += __shfl_xor(a6, m, 64); a7 += __shfl_xor(a7, m, 64);
    }
    if (g == 0){
        float inv = 1.f / (float)max(e1 - e0, 1);
        uintx4 rr = *(const uintx4*)(yr + (size_t)v*256 + 128 + c*8);
        uintx4 bb = *(const uintx4*)(bias + c*8);
        float v0 = a0*inv + bflo(rr.x) + bflo(bb.x);
        float v1 = a1*inv + bfhi(rr.x) + bfhi(bb.x);
        float v2 = a2*inv + bflo(rr.y) + bflo(bb.y);
        float v3 = a3*inv + bfhi(rr.y) + bfhi(bb.y);
        float v4 = a4*inv + bflo(rr.z) + bflo(bb.z);
        float v5 = a5*inv + bfhi(rr.z) + bfhi(bb.z);
        float v6 = a6*inv + bflo(rr.w) + bflo(bb.w);
        float v7 = a7*inv + bfhi(rr.w) + bfhi(bb.w);
        if (do_relu){
            v0=fmaxf(v0,0.f); v1=fmaxf(v1,0.f); v2=fmaxf(v2,0.f); v3=fmaxf(v3,0.f);
            v4=fmaxf(v4,0.f); v5=fmaxf(v5,0.f); v6=fmaxf(v6,0.f); v7=fmaxf(v7,0.f);
        }
        uintx4 o;
        o.x = (unsigned)f2bf(v0) | ((unsigned)f2bf(v1) << 16);
        o.y = (unsigned)f2bf(v2) | ((unsigned)f2bf(v3) << 16);
        o.z = (unsigned)f2bf(v4) | ((unsigned)f2bf(v5) << 16);
        o.w = (unsigned)f2bf(v6) | ((unsigned)f2bf(v7) << 16);
        *(uintx4*)(out + (size_t)v*128 + c*8) = o;
    }
}

// ---------------- MFMA predictor: one block = 64 batch rows ----------------
__global__ __launch_bounds__(256)
void k_pred2(const ushort_t* __restrict__ h2,
             const void* __restrict__ srcn, const void* __restrict__ tgtn,
             const ushort_t* __restrict__ cw, const ushort_t* __restrict__ bpp1,
             const ushort_t* __restrict__ bpp2, const float* __restrict__ bnf,
             void* __restrict__ outp, const int* __restrict__ flags)
{
    __shared__ ushort_t comb[64][328];    // 320 cols + 8 pad (2-way LDS = free)
    __shared__ ushort_t zbuf[64][136];
    __shared__ ushort_t z2buf[64][68];
    __shared__ float    partial[4][64];
    __shared__ int      sid[64], tid_[64];

    const int t    = threadIdx.x;
    const int lane = t & 63;
    const int w    = t >> 6;
    const int l16  = lane & 15;
    const int q    = lane >> 4;
    const int row0 = blockIdx.x * 64;
    const int i64  = flags[1];

    if (t < 64){ sid[t] = geti(srcn, row0 + t, i64); tid_[t] = geti(tgtn, row0 + t, i64); }
    __syncthreads();

    const unsigned* h2u = (const unsigned*)h2;
    #pragma unroll 4
    for (int r = w*16; r < w*16 + 16; ++r){
        unsigned us = h2u[(size_t)sid[r]*64 + lane];
        unsigned ut = h2u[(size_t)tid_[r]*64 + lane];
        *(unsigned*)&comb[r][2*lane]       = us;
        *(unsigned*)&comb[r][128 + 2*lane] = ut;
    }
    {
        int r = t >> 2, c0 = (t & 3) * 16;
        float efv[6];
        #pragma unroll
        for (int k = 0; k < 6; ++k) efv[k] = bf1(cw[OFF_EF + (row0 + r)*6 + k]);
        #pragma unroll
        for (int c = 0; c < 16; ++c){
            int n = c0 + c;
            float a = bf1(cw[OFF_EPB + n]);
            #pragma unroll
            for (int k = 0; k < 6; ++k) a += efv[k] * bf1(cw[OFF_EPW + k*64 + n]);
            comb[r][256 + n] = f2bf(fmaxf(a, 0.f));
        }
    }
    __syncthreads();

    floatx4 acc[4][2] = {};
    for (int kk = 0; kk < 10; ++kk){
        short8 a[4];
        #pragma unroll
        for (int rt = 0; rt < 4; ++rt)
            a[rt] = *(const short8*)&comb[rt*16 + l16][kk*32 + q*8];
        #pragma unroll
        for (int ci = 0; ci < 2; ++ci){
            short8 b = *(const short8*)&bpp1[(((kk*8) + (w*2 + ci))*64 + lane)*8];
            #pragma unroll
            for (int rt = 0; rt < 4; ++rt)
                acc[rt][ci] = __builtin_amdgcn_mfma_f32_16x16x32_bf16(a[rt], b, acc[rt][ci], 0, 0, 0);
        }
    }
    #pragma unroll
    for (int ci = 0; ci < 2; ++ci){
        int n = w*32 + ci*16 + l16;
        float b1v = bf1(cw[OFF_P1B + n]);
        float sc = bnf[n], sh = bnf[128 + n];
        #pragma unroll
        for (int rt = 0; rt < 4; ++rt)
            #pragma unroll
            for (int r = 0; r < 4; ++r){
                float v = fmaxf(acc[rt][ci][r] + b1v, 0.f) * sc + sh;
                zbuf[rt*16 + q*4 + r][n] = f2bf(v);
            }
    }
    __syncthreads();

    floatx4 acc2[4] = {};
    for (int kk = 0; kk < 4; ++kk){
        short8 b = *(const short8*)&bpp2[(((kk*4) + w)*64 + lane)*8];
        #pragma unroll
        for (int rt = 0; rt < 4; ++rt){
            short8 a = *(const short8*)&zbuf[rt*16 + l16][kk*32 + q*8];
            acc2[rt] = __builtin_amdgcn_mfma_f32_16x16x32_bf16(a, b, acc2[rt], 0, 0, 0);
        }
    }
    {
        int n = w*16 + l16;
        float b2v = bf1(cw[OFF_P2B + n]);
        #pragma unroll
        for (int rt = 0; rt < 4; ++rt)
            #pragma unroll
            for (int r = 0; r < 4; ++r)
                z2buf[rt*16 + q*4 + r][n] = f2bf(fmaxf(acc2[rt][r] + b2v, 0.f));
    }
    __syncthreads();

    {
        int r = t & 63, seg = t >> 6;
        float s = 0.f;
        #pragma unroll
        for (int c = 0; c < 16; ++c){
            int n = seg*16 + c;
            s += bf1(z2buf[r][n]) * bf1(cw[OFF_P3W + n]);
        }
        partial[seg][r] = s;
    }
    __syncthreads();
    if (t < 64){
        float zf = partial[0][t] + partial[1][t] + partial[2][t] + partial[3][t] + bf1(cw[OFF_P3B]);
        float sg = 1.f / (1.f + __expf(-zf));
        if (flags[0]) ((float*)outp)[row0 + t] = sg;
        else          ((ushort_t*)outp)[row0 + t] = f2bf(sg);
    }
}

extern "C" void kernel_launch(void* const* d_in, const int* in_sizes, int n_in,
                              void* d_out, int out_size, void* d_ws, size_t ws_size,
                              hipStream_t stream)
{
    const void* x    = d_in[0];
    const void* ei   = d_in[1];
    const void* srcn = d_in[2];
    const void* tgtn = d_in[3];

    char* p = (char*)d_ws;
    auto carve = [&](size_t bytes)->char*{ char* r = p; p += (bytes + 511) & ~size_t(511); return r; };
    int* flags = (int*)carve(64);
    int* off   = (int*)carve((N_NODES+1)*4);
    int* btot  = (int*)carve(NBUCK*4);
    int* bbase = (int*)carve((NBUCK+1)*4);
    ushort_t* csr = (ushort_t*)carve((size_t)N_EDGES*2);
    ushort_t* yr  = (ushort_t*)carve((size_t)N_NODES*256*2);
    ushort_t* h   = (ushort_t*)carve((size_t)N_NODES*128*2);
    ushort_t* cw  = (ushort_t*)carve((size_t)CW_TOT*2);
    ushort_t* bp0 = (ushort_t*)carve((size_t)65536*2);
    ushort_t* bp1 = (ushort_t*)carve((size_t)32768*2);
    ushort_t* bpp1= (ushort_t*)carve((size_t)40960*2);
    ushort_t* bpp2= (ushort_t*)carve((size_t)8192*2);
    float*    bnf = (float*)carve(256*4);
    ushort_t* xbf = (ushort_t*)carve((size_t)N_NODES*256*2);

    // alias scratch that dies before k_gemm2 writes yr:
    int*      hist = (int*)yr;                               // 3.128 MB
    unsigned* ebuf = (unsigned*)((char*)yr + 8u*1024*1024);  // 6.4 MB

    k_detect<<<1, 64, 0, stream>>>((const unsigned*)x, (const unsigned*)ei, flags);

    ConvDesc cd;
    const int srcidx[NT] = {5,7,8,10,6,9,11,12,13,14,15,16,17,18,19,20,21,4,22};
    const int lens[NT]   = {32768,32768,16384,16384,128,128,384,64,40960,128,128,128,128,128,8192,64,64,98304,1};
    int run = 0;
    for (int i = 0; i < NT; ++i){ cd.src[i] = d_in[srcidx[i]]; cd.cum[i] = run; run += lens[i]; }
    cd.cum[NT] = run;
    k_conv<<<(CW_TOT+255)/256, 256, 0, stream>>>(cd, cw, flags);
    k_pack<<<(PACK_TOT+255)/256, 256, 0, stream>>>(cw, bp0, bp1, bpp1, bpp2, bnf);
    k_xcast<<<12500, 256, 0, stream>>>((const float*)x, xbf, flags);

    kb_hist    <<<NBLK, 256, 0, stream>>>(ei, hist, flags);
    kb_scancol <<<NBUCK, 1024, 0, stream>>>(hist, btot);
    kb_scanbase<<<1, 1024, 0, stream>>>(btot, bbase, off);
    kb_scatter <<<NBLK, 256, 0, stream>>>(ei, hist, bbase, ebuf, flags);
    kb_csr     <<<NBUCK, 256, 0, stream>>>(ebuf, bbase, csr, off);

    int gblocks = (N_NODES + 63) / 64;   // 782
    k_gemm2<8, true ><<<gblocks, 256, 0, stream>>>(x, xbf, bp0, yr, N_NODES, flags);
    k_agg<<<(N_NODES+3)/4, 256, 0, stream>>>(off, csr, yr, cw+OFF_B0, h, 1);
    k_gemm2<4, false><<<gblocks, 256, 0, stream>>>(h, nullptr, bp1, yr, N_NODES, flags);
    k_agg<<<(N_NODES+3)/4, 256, 0, stream>>>(off, csr, yr, cw+OFF_B1, h, 0);

    k_pred2<<<BATCH/64, 256, 0, stream>>>(h, srcn, tgtn, cw, bpp1, bpp2, bnf, d_out, flags);
}